// Round 2
// baseline (1285.269 us; speedup 1.0000x reference)
//
#include <hip/hip_runtime.h>
#include <hip/hip_bf16.h>
#include <stdint.h>

// Problem constants (fixed by setup_inputs)
#define T_TOK 8192
#define D_DIM 1024
#define H_DIM 2048
#define E_NUM 8
#define CAP   1280       // int(1.25 * T / E)
#define CAP2  2560       // 2*CAP slots per expert (k=0 block then k=1 block)

#define BM 128
#define BN 128
#define BK 32

typedef __attribute__((ext_vector_type(8))) short short8;   // 8 bf16 (4 VGPRs)
typedef __attribute__((ext_vector_type(4))) float float4v;  // MFMA C/D

static __device__ __forceinline__ unsigned short f2bf(float f) {
    unsigned int u = __float_as_uint(f);
    unsigned int r = (u + 0x7FFFu + ((u >> 16) & 1u)) >> 16;  // RNE
    return (unsigned short)r;
}

static __device__ __forceinline__ void store4bf(unsigned short* d, float4 v) {
    union { unsigned short u[4]; uint2 q; } pk;
    pk.u[0] = f2bf(v.x); pk.u[1] = f2bf(v.y);
    pk.u[2] = f2bf(v.z); pk.u[3] = f2bf(v.w);
    *(uint2*)d = pk.q;
}

// ---------------------------------------------------------------------------
// Router: one wave per token. fp32 logits -> softmax -> top2 -> normalized w.
// Tie-breaking matches jax.lax.top_k: lowest index wins on equal values.
// ---------------------------------------------------------------------------
__global__ __launch_bounds__(64) void router_k(
    const float* __restrict__ x, const float* __restrict__ gw,
    int* __restrict__ topi, float* __restrict__ topw) {
    const int t = blockIdx.x;
    const int lane = threadIdx.x;
    const float* xr = x + (size_t)t * D_DIM;

    float p[E_NUM];
#pragma unroll
    for (int e = 0; e < E_NUM; ++e) p[e] = 0.f;
#pragma unroll
    for (int c = 0; c < 4; ++c) {
        const int idx = c * 256 + lane * 4;
        const float4 xv = *(const float4*)(xr + idx);
#pragma unroll
        for (int e = 0; e < E_NUM; ++e) {
            const float4 gv = *(const float4*)(gw + e * D_DIM + idx);
            p[e] += xv.x * gv.x + xv.y * gv.y + xv.z * gv.z + xv.w * gv.w;
        }
    }
#pragma unroll
    for (int e = 0; e < E_NUM; ++e) {
        float v = p[e];
#pragma unroll
        for (int off = 32; off >= 1; off >>= 1) v += __shfl_xor(v, off);
        p[e] = v;
    }
    if (lane == 0) {
        float mx = p[0];
#pragma unroll
        for (int e = 1; e < E_NUM; ++e) mx = fmaxf(mx, p[e]);
        float pe[E_NUM]; float s = 0.f;
#pragma unroll
        for (int e = 0; e < E_NUM; ++e) { pe[e] = expf(p[e] - mx); s += pe[e]; }
        const float inv = 1.f / s;
        int i0 = 0;
#pragma unroll
        for (int e = 1; e < E_NUM; ++e) if (pe[e] > pe[i0]) i0 = e;
        int i1 = -1;
#pragma unroll
        for (int e = 0; e < E_NUM; ++e) {
            if (e == i0) continue;
            if (i1 < 0 || pe[e] > pe[i1]) i1 = e;
        }
        const float p0 = pe[i0] * inv, p1 = pe[i1] * inv;
        const float wn = 1.f / (p0 + p1 + 1e-9f);
        topi[t * 2 + 0] = i0; topi[t * 2 + 1] = i1;
        topw[t * 2 + 0] = p0 * wn; topw[t * 2 + 1] = p1 * wn;
    }
}

// ---------------------------------------------------------------------------
// Assignment: one block, 16 waves; wave (k,e) scans tokens in order.
// Reproduces rank = cumsum(one_hot)-1 per (k,e) and capacity truncation.
// List layout per expert: [k=0 kept tokens][k=1 kept tokens][pad: tok=0,w=0].
// ---------------------------------------------------------------------------
__global__ __launch_bounds__(1024) void assign_k(
    const int* __restrict__ topi, const float* __restrict__ topw,
    int* __restrict__ tok_list, float* __restrict__ w_list,
    int* __restrict__ n_tot) {
    __shared__ int kept[2][E_NUM];
    __shared__ int ntotL[E_NUM];
    const int tid = threadIdx.x;
    const int wid = tid >> 6, lane = tid & 63;
    const int k = wid >> 3, e = wid & 7;
    const uint64_t lt = (1ull << lane) - 1ull;

    // phase 1: total per-(k,e) counts
    int total = 0;
    for (int base = 0; base < T_TOK; base += 64) {
        const int idx = topi[(base + lane) * 2 + k];
        total += __popcll(__ballot(idx == e));
    }
    if (lane == 0) kept[k][e] = min(total, CAP);
    __syncthreads();
    if (tid < E_NUM) {
        ntotL[tid] = kept[0][tid] + kept[1][tid];
        n_tot[tid] = ntotL[tid];
    }
    const int myBase = e * CAP2 + (k ? kept[0][e] : 0);

    // phase 2: ordered compaction of kept tokens
    int running = 0, keptRun = 0;
    for (int base = 0; base < T_TOK; base += 64) {
        const int t = base + lane;
        const bool pred = (topi[t * 2 + k] == e);
        const uint64_t m = __ballot(pred);
        const int rank = running + __popcll(m & lt);
        const bool keep = pred && (rank < CAP);
        const uint64_t km = __ballot(keep);
        if (keep) {
            const int slot = myBase + keptRun + __popcll(km & lt);
            tok_list[slot] = t;
            w_list[slot] = topw[t * 2 + k];
        }
        running += __popcll(m);
        keptRun += __popcll(km);
    }
    __syncthreads();
    // phase 3: pad unused slots (safe token 0, zero weight)
    for (int s = tid; s < E_NUM * CAP2; s += 1024) {
        const int ee = s / CAP2, ls = s - ee * CAP2;
        if (ls >= ntotL[ee]) { tok_list[s] = 0; w_list[s] = 0.f; }
    }
}

// ---------------------------------------------------------------------------
// Fused gate+up GEMM: h = silu(Xe@Wg^T) * (Xe@Wu^T), bf16 MFMA, fp32 acc.
// A: gathered x rows (fp32 -> bf16 in staging). B: weight rows [N][K] native.
// e = e0 + blockIdx.z; h_ws is indexed by the chunk-local expert blockIdx.z.
// ---------------------------------------------------------------------------
__global__ __launch_bounds__(256, 2) void gateup_k(
    const float* __restrict__ x,
    const float* __restrict__ wg_all, const float* __restrict__ wu_all,
    const int* __restrict__ tok_list, const int* __restrict__ n_tot,
    unsigned short* __restrict__ h_ws, int e0) {
    const int ez = blockIdx.z;
    const int e = e0 + ez;
    const int m0 = blockIdx.y * BM;
    if (m0 >= n_tot[e]) return;
    const int n0 = blockIdx.x * BN;

    __shared__ __align__(16) unsigned short As[BM][BK];
    __shared__ __align__(16) unsigned short Bg[BN][BK];
    __shared__ __align__(16) unsigned short Bu[BN][BK];
    __shared__ int tokL[BM];

    const int tid = threadIdx.x;
    if (tid < BM) tokL[tid] = tok_list[e * CAP2 + m0 + tid];
    __syncthreads();

    const float* wg = wg_all + (size_t)e * H_DIM * D_DIM;
    const float* wu = wu_all + (size_t)e * H_DIM * D_DIM;

    const float* aSrc[4]; const float* gSrc[4]; const float* uSrc[4];
    unsigned short* aDst[4]; unsigned short* gDst[4]; unsigned short* uDst[4];
#pragma unroll
    for (int it = 0; it < 4; ++it) {
        const int fid = it * 256 + tid;
        const int row = fid >> 3;
        const int c4 = (fid & 7) * 4;
        aSrc[it] = x + (size_t)tokL[row] * D_DIM + c4;
        gSrc[it] = wg + (size_t)(n0 + row) * D_DIM + c4;
        uSrc[it] = wu + (size_t)(n0 + row) * D_DIM + c4;
        aDst[it] = &As[row][c4];
        gDst[it] = &Bg[row][c4];
        uDst[it] = &Bu[row][c4];
    }

    float4v accg[4][4], accu[4][4];
#pragma unroll
    for (int i = 0; i < 4; ++i)
#pragma unroll
        for (int j = 0; j < 4; ++j) {
            accg[i][j] = (float4v){0.f, 0.f, 0.f, 0.f};
            accu[i][j] = (float4v){0.f, 0.f, 0.f, 0.f};
        }

    const int wid = tid >> 6, lane = tid & 63;
    const int wm = (wid & 1) * 64, wn = (wid >> 1) * 64;
    const int frow = lane & 15;
    const int fk = (lane >> 4) * 8;

    for (int k0 = 0; k0 < D_DIM; k0 += BK) {
#pragma unroll
        for (int it = 0; it < 4; ++it) {
            const float4 av = *(const float4*)(aSrc[it] + k0);
            const float4 gv = *(const float4*)(gSrc[it] + k0);
            const float4 uv = *(const float4*)(uSrc[it] + k0);
            store4bf(aDst[it], av);
            store4bf(gDst[it], gv);
            store4bf(uDst[it], uv);
        }
        __syncthreads();
        short8 af[4], bgf[4], buf[4];
#pragma unroll
        for (int i = 0; i < 4; ++i)
            af[i] = *(const short8*)&As[wm + i * 16 + frow][fk];
#pragma unroll
        for (int j = 0; j < 4; ++j) {
            bgf[j] = *(const short8*)&Bg[wn + j * 16 + frow][fk];
            buf[j] = *(const short8*)&Bu[wn + j * 16 + frow][fk];
        }
#pragma unroll
        for (int i = 0; i < 4; ++i)
#pragma unroll
            for (int j = 0; j < 4; ++j) {
                accg[i][j] = __builtin_amdgcn_mfma_f32_16x16x32_bf16(af[i], bgf[j], accg[i][j], 0, 0, 0);
                accu[i][j] = __builtin_amdgcn_mfma_f32_16x16x32_bf16(af[i], buf[j], accu[i][j], 0, 0, 0);
            }
        __syncthreads();
    }

    // epilogue: h = silu(g)*u  (C/D: col=lane&15, row=(lane>>4)*4+reg)
    const int col = lane & 15, rbase = (lane >> 4) * 4;
#pragma unroll
    for (int i = 0; i < 4; ++i)
#pragma unroll
        for (int j = 0; j < 4; ++j)
#pragma unroll
            for (int r = 0; r < 4; ++r) {
                const float g = accg[i][j][r];
                const float u = accu[i][j][r];
                const float hv = (g / (1.f + __expf(-g))) * u;
                const int m = wm + i * 16 + rbase + r;
                const int n = wn + j * 16 + col;
                h_ws[((size_t)ez * CAP2 + m0 + m) * H_DIM + (n0 + n)] = f2bf(hv);
            }
}

// ---------------------------------------------------------------------------
// Down GEMM: y = h @ Wd^T, scaled by routing weight, atomic-add into out.
// ---------------------------------------------------------------------------
__global__ __launch_bounds__(256, 2) void down_k(
    const unsigned short* __restrict__ h_ws, const float* __restrict__ wd_all,
    const int* __restrict__ tok_list, const float* __restrict__ w_list,
    const int* __restrict__ n_tot, float* __restrict__ out, int e0) {
    const int ez = blockIdx.z;
    const int e = e0 + ez;
    const int m0 = blockIdx.y * BM;
    if (m0 >= n_tot[e]) return;
    const int n0 = blockIdx.x * BN;

    __shared__ __align__(16) unsigned short As[BM][BK];
    __shared__ __align__(16) unsigned short Bs[BN][BK];
    __shared__ int tokL[BM];
    __shared__ float wL[BM];

    const int tid = threadIdx.x;
    if (tid < BM) {
        tokL[tid] = tok_list[e * CAP2 + m0 + tid];
        wL[tid] = w_list[e * CAP2 + m0 + tid];
    }
    __syncthreads();

    const unsigned short* hA = h_ws + ((size_t)ez * CAP2 + m0) * H_DIM;
    const float* wd = wd_all + (size_t)e * D_DIM * H_DIM;

    const unsigned short* aSrc[2]; unsigned short* aDst[2];
#pragma unroll
    for (int it = 0; it < 2; ++it) {
        const int fid = it * 256 + tid;
        const int row = fid >> 2;
        const int c8 = (fid & 3) * 8;
        aSrc[it] = hA + (size_t)row * H_DIM + c8;
        aDst[it] = &As[row][c8];
    }
    const float* bSrc[4]; unsigned short* bDst[4];
#pragma unroll
    for (int it = 0; it < 4; ++it) {
        const int fid = it * 256 + tid;
        const int row = fid >> 3;
        const int c4 = (fid & 7) * 4;
        bSrc[it] = wd + (size_t)(n0 + row) * H_DIM + c4;
        bDst[it] = &Bs[row][c4];
    }

    float4v acc[4][4];
#pragma unroll
    for (int i = 0; i < 4; ++i)
#pragma unroll
        for (int j = 0; j < 4; ++j) acc[i][j] = (float4v){0.f, 0.f, 0.f, 0.f};

    const int wid = tid >> 6, lane = tid & 63;
    const int wm = (wid & 1) * 64, wn = (wid >> 1) * 64;
    const int frow = lane & 15;
    const int fk = (lane >> 4) * 8;

    for (int k0 = 0; k0 < H_DIM; k0 += BK) {
#pragma unroll
        for (int it = 0; it < 2; ++it)
            *(uint4*)aDst[it] = *(const uint4*)(aSrc[it] + k0);
#pragma unroll
        for (int it = 0; it < 4; ++it)
            store4bf(bDst[it], *(const float4*)(bSrc[it] + k0));
        __syncthreads();
        short8 af[4], bf[4];
#pragma unroll
        for (int i = 0; i < 4; ++i)
            af[i] = *(const short8*)&As[wm + i * 16 + frow][fk];
#pragma unroll
        for (int j = 0; j < 4; ++j)
            bf[j] = *(const short8*)&Bs[wn + j * 16 + frow][fk];
#pragma unroll
        for (int i = 0; i < 4; ++i)
#pragma unroll
            for (int j = 0; j < 4; ++j)
                acc[i][j] = __builtin_amdgcn_mfma_f32_16x16x32_bf16(af[i], bf[j], acc[i][j], 0, 0, 0);
        __syncthreads();
    }

    const int col = lane & 15, rbase = (lane >> 4) * 4;
#pragma unroll
    for (int i = 0; i < 4; ++i)
#pragma unroll
        for (int j = 0; j < 4; ++j)
#pragma unroll
            for (int r = 0; r < 4; ++r) {
                const int m = wm + i * 16 + rbase + r;
                const int n = wn + j * 16 + col;
                const float v = acc[i][j][r] * wL[m];
                unsafeAtomicAdd(&out[(size_t)tokL[m] * D_DIM + n0 + n], v);
            }
}

// ---------------------------------------------------------------------------
extern "C" void kernel_launch(void* const* d_in, const int* in_sizes, int n_in,
                              void* d_out, int out_size, void* d_ws, size_t ws_size,
                              hipStream_t stream) {
    const float* x        = (const float*)d_in[0];
    const float* gate_w   = (const float*)d_in[1];
    const float* gate_pw  = (const float*)d_in[2];
    const float* up_pw    = (const float*)d_in[3];
    const float* down_pw  = (const float*)d_in[4];
    float* out = (float*)d_out;

    // workspace layout: small routing arrays first (guaranteed fit), then h.
    uint8_t* ws = (uint8_t*)d_ws;
    size_t off = 0;
    int*   topi     = (int*)(ws + off);   off += (size_t)T_TOK * 2 * 4;      // 64 KB
    float* topw     = (float*)(ws + off); off += (size_t)T_TOK * 2 * 4;      // 64 KB
    int*   tok_list = (int*)(ws + off);   off += (size_t)E_NUM * CAP2 * 4;   // 80 KB
    float* w_list   = (float*)(ws + off); off += (size_t)E_NUM * CAP2 * 4;   // 80 KB
    int*   n_tot    = (int*)(ws + off);   off += 256;
    off = (off + 255) & ~(size_t)255;
    unsigned short* h_ws = (unsigned short*)(ws + off);
    const size_t per_e = (size_t)CAP2 * H_DIM * 2;                           // 10.5 MB / expert

    // Expert chunking: as many experts' h-buffers as fit in the remaining ws.
    // ws_size is constant across calls -> identical launch sequence, graph-safe.
    int chunk = (ws_size > off) ? (int)((ws_size - off) / per_e) : 0;
    if (chunk > E_NUM) chunk = E_NUM;
    if (chunk < 1) chunk = 1;   // last resort; harness ws is expected >> 11 MB
    (void)n_in; (void)in_sizes; (void)out_size;

    hipMemsetAsync(out, 0, (size_t)T_TOK * D_DIM * sizeof(float), stream);

    router_k<<<T_TOK, 64, 0, stream>>>(x, gate_w, topi, topw);
    assign_k<<<1, 1024, 0, stream>>>(topi, topw, tok_list, w_list, n_tot);

    for (int e0 = 0; e0 < E_NUM; e0 += chunk) {
        const int ne = (e0 + chunk <= E_NUM) ? chunk : (E_NUM - e0);
        dim3 g1(H_DIM / BN, CAP2 / BM, ne);   // (16, 20, ne)
        gateup_k<<<g1, 256, 0, stream>>>(x, gate_pw, up_pw, tok_list, n_tot, h_ws, e0);
        dim3 g2(D_DIM / BN, CAP2 / BM, ne);   // (8, 20, ne)
        down_k<<<g2, 256, 0, stream>>>(h_ws, down_pw, tok_list, w_list, n_tot, out, e0);
    }
}

// Round 3
// 715.410 us; speedup vs baseline: 1.7965x; 1.7965x over previous
//
#include <hip/hip_runtime.h>
#include <hip/hip_bf16.h>
#include <stdint.h>

// Problem constants (fixed by setup_inputs)
#define T_TOK 8192
#define D_DIM 1024
#define H_DIM 2048
#define E_NUM 8
#define CAP   1280       // int(1.25 * T / E)
#define CAP2  2560       // 2*CAP slots per expert (k=0 block then k=1 block)

#define BM 128
#define BN 128
#define BK 32

typedef __attribute__((ext_vector_type(8))) short short8;   // 8 bf16 (4 VGPRs)
typedef __attribute__((ext_vector_type(4))) float float4v;  // MFMA C/D
typedef __attribute__((address_space(1))) const unsigned int gu32;
typedef __attribute__((address_space(3))) unsigned int lu32;

static __device__ __forceinline__ unsigned short f2bf(float f) {
    unsigned int u = __float_as_uint(f);
    unsigned int r = (u + 0x7FFFu + ((u >> 16) & 1u)) >> 16;  // RNE
    return (unsigned short)r;
}

static __device__ __forceinline__ void store4bf(unsigned short* d, float4 v) {
    union { unsigned short u[4]; uint2 q; } pk;
    pk.u[0] = f2bf(v.x); pk.u[1] = f2bf(v.y);
    pk.u[2] = f2bf(v.z); pk.u[3] = f2bf(v.w);
    *(uint2*)d = pk.q;
}

// ---------------------------------------------------------------------------
// fp32 -> bf16 streaming conversion (one-time preprocessing)
// ---------------------------------------------------------------------------
__global__ __launch_bounds__(256) void convert_k(
    const float* __restrict__ src, unsigned short* __restrict__ dst, int n4) {
    const int i = blockIdx.x * 256 + threadIdx.x;
    if (i >= n4) return;
    store4bf(dst + (size_t)i * 4, ((const float4*)src)[i]);
}

// ---------------------------------------------------------------------------
// Router: one wave per token. fp32 logits -> softmax -> top2 -> normalized w.
// ---------------------------------------------------------------------------
__global__ __launch_bounds__(64) void router_k(
    const float* __restrict__ x, const float* __restrict__ gw,
    int* __restrict__ topi, float* __restrict__ topw) {
    const int t = blockIdx.x;
    const int lane = threadIdx.x;
    const float* xr = x + (size_t)t * D_DIM;

    float p[E_NUM];
#pragma unroll
    for (int e = 0; e < E_NUM; ++e) p[e] = 0.f;
#pragma unroll
    for (int c = 0; c < 4; ++c) {
        const int idx = c * 256 + lane * 4;
        const float4 xv = *(const float4*)(xr + idx);
#pragma unroll
        for (int e = 0; e < E_NUM; ++e) {
            const float4 gv = *(const float4*)(gw + e * D_DIM + idx);
            p[e] += xv.x * gv.x + xv.y * gv.y + xv.z * gv.z + xv.w * gv.w;
        }
    }
#pragma unroll
    for (int e = 0; e < E_NUM; ++e) {
        float v = p[e];
#pragma unroll
        for (int off = 32; off >= 1; off >>= 1) v += __shfl_xor(v, off);
        p[e] = v;
    }
    if (lane == 0) {
        float mx = p[0];
#pragma unroll
        for (int e = 1; e < E_NUM; ++e) mx = fmaxf(mx, p[e]);
        float pe[E_NUM]; float s = 0.f;
#pragma unroll
        for (int e = 0; e < E_NUM; ++e) { pe[e] = expf(p[e] - mx); s += pe[e]; }
        const float inv = 1.f / s;
        int i0 = 0;
#pragma unroll
        for (int e = 1; e < E_NUM; ++e) if (pe[e] > pe[i0]) i0 = e;
        int i1 = -1;
#pragma unroll
        for (int e = 0; e < E_NUM; ++e) {
            if (e == i0) continue;
            if (i1 < 0 || pe[e] > pe[i1]) i1 = e;
        }
        const float p0 = pe[i0] * inv, p1 = pe[i1] * inv;
        const float wn = 1.f / (p0 + p1 + 1e-9f);
        topi[t * 2 + 0] = i0; topi[t * 2 + 1] = i1;
        topw[t * 2 + 0] = p0 * wn; topw[t * 2 + 1] = p1 * wn;
    }
}

// ---------------------------------------------------------------------------
// Assignment: one block, 16 waves; wave (k,e) scans tokens in order.
// ---------------------------------------------------------------------------
__global__ __launch_bounds__(1024) void assign_k(
    const int* __restrict__ topi, const float* __restrict__ topw,
    int* __restrict__ tok_list, float* __restrict__ w_list,
    int* __restrict__ n_tot) {
    __shared__ int kept[2][E_NUM];
    __shared__ int ntotL[E_NUM];
    const int tid = threadIdx.x;
    const int wid = tid >> 6, lane = tid & 63;
    const int k = wid >> 3, e = wid & 7;
    const uint64_t lt = (1ull << lane) - 1ull;

    int total = 0;
    for (int base = 0; base < T_TOK; base += 64) {
        const int idx = topi[(base + lane) * 2 + k];
        total += __popcll(__ballot(idx == e));
    }
    if (lane == 0) kept[k][e] = min(total, CAP);
    __syncthreads();
    if (tid < E_NUM) {
        ntotL[tid] = kept[0][tid] + kept[1][tid];
        n_tot[tid] = ntotL[tid];
    }
    const int myBase = e * CAP2 + (k ? kept[0][e] : 0);

    int running = 0, keptRun = 0;
    for (int base = 0; base < T_TOK; base += 64) {
        const int t = base + lane;
        const bool pred = (topi[t * 2 + k] == e);
        const uint64_t m = __ballot(pred);
        const int rank = running + __popcll(m & lt);
        const bool keep = pred && (rank < CAP);
        const uint64_t km = __ballot(keep);
        if (keep) {
            const int slot = myBase + keptRun + __popcll(km & lt);
            tok_list[slot] = t;
            w_list[slot] = topw[t * 2 + k];
        }
        running += __popcll(m);
        keptRun += __popcll(km);
    }
    __syncthreads();
    for (int s = tid; s < E_NUM * CAP2; s += 1024) {
        const int ee = s / CAP2, ls = s - ee * CAP2;
        if (ls >= ntotL[ee]) { tok_list[s] = 0; w_list[s] = 0.f; }
    }
}

// ---------------------------------------------------------------------------
// Fused gate+up GEMM, bf16 path: global_load_lds width-16 staging.
// LDS region: As(8KB) | Bg(8KB) | Bu(8KB). Wave w stages 6 KB: insts i=0..5,
// flat16 index f = (w*6+i)*64 + lane; LDS dest = smem + (w*6+i)*1024 + lane*16
// (hardware-implied). Global side is per-lane (gather for A rows is legal).
// ---------------------------------------------------------------------------
__global__ __launch_bounds__(256, 2) void gateup_bf_k(
    const unsigned short* __restrict__ xbf,
    const unsigned short* __restrict__ wgbf, const unsigned short* __restrict__ wubf,
    const int* __restrict__ tok_list, const int* __restrict__ n_tot,
    unsigned short* __restrict__ h_ws, int e0) {
    const int ez = blockIdx.z;
    const int e = e0 + ez;
    const int m0 = blockIdx.y * BM;
    if (m0 >= n_tot[e]) return;
    const int n0 = blockIdx.x * BN;

    __shared__ __align__(1024) unsigned short smem[12288];   // 24 KB

    const int tid = threadIdx.x, wid = tid >> 6, lane = tid & 63;

    const unsigned short* gsrc[6];
    int ldsoff[6];
#pragma unroll
    for (int i = 0; i < 6; ++i) {
        const int f = (wid * 6 + i) * 64 + lane;
        const unsigned short* g;
        if (f < 512) {
            const int row = f >> 2;
            const int tok = tok_list[e * CAP2 + m0 + row];
            g = xbf + (size_t)tok * D_DIM + (f & 3) * 8;
        } else if (f < 1024) {
            const int r = (f - 512) >> 2;
            g = wgbf + ((size_t)e * H_DIM + n0 + r) * D_DIM + (f & 3) * 8;
        } else {
            const int r = (f - 1024) >> 2;
            g = wubf + ((size_t)e * H_DIM + n0 + r) * D_DIM + (f & 3) * 8;
        }
        gsrc[i] = g;
        ldsoff[i] = (wid * 6 + i) * 1024;   // bytes, wave-uniform
    }

    float4v accg[4][4], accu[4][4];
#pragma unroll
    for (int i = 0; i < 4; ++i)
#pragma unroll
        for (int j = 0; j < 4; ++j) {
            accg[i][j] = (float4v){0.f, 0.f, 0.f, 0.f};
            accu[i][j] = (float4v){0.f, 0.f, 0.f, 0.f};
        }

    const int wm = (wid & 1) * 64, wn = (wid >> 1) * 64;
    const int frow = lane & 15;
    const int fk = (lane >> 4) * 8;

    for (int k0 = 0; k0 < D_DIM; k0 += BK) {
#pragma unroll
        for (int i = 0; i < 6; ++i)
            __builtin_amdgcn_global_load_lds(
                (gu32*)(gsrc[i] + k0),
                (lu32*)((char*)smem + ldsoff[i]), 16, 0, 0);
        __syncthreads();

        short8 af[4], bgf[4], buf[4];
#pragma unroll
        for (int i = 0; i < 4; ++i)
            af[i] = *(const short8*)&smem[(wm + i * 16 + frow) * 32 + fk];
#pragma unroll
        for (int j = 0; j < 4; ++j) {
            bgf[j] = *(const short8*)&smem[4096 + (wn + j * 16 + frow) * 32 + fk];
            buf[j] = *(const short8*)&smem[8192 + (wn + j * 16 + frow) * 32 + fk];
        }
#pragma unroll
        for (int i = 0; i < 4; ++i)
#pragma unroll
            for (int j = 0; j < 4; ++j) {
                accg[i][j] = __builtin_amdgcn_mfma_f32_16x16x32_bf16(af[i], bgf[j], accg[i][j], 0, 0, 0);
                accu[i][j] = __builtin_amdgcn_mfma_f32_16x16x32_bf16(af[i], buf[j], accu[i][j], 0, 0, 0);
            }
        __syncthreads();
    }

    const int col = lane & 15, rbase = (lane >> 4) * 4;
#pragma unroll
    for (int i = 0; i < 4; ++i)
#pragma unroll
        for (int j = 0; j < 4; ++j)
#pragma unroll
            for (int r = 0; r < 4; ++r) {
                const float g = accg[i][j][r];
                const float u = accu[i][j][r];
                const float hv = (g / (1.f + __expf(-g))) * u;
                const int m = wm + i * 16 + rbase + r;
                const int n = wn + j * 16 + col;
                h_ws[((size_t)ez * CAP2 + m0 + m) * H_DIM + (n0 + n)] = f2bf(hv);
            }
}

// ---------------------------------------------------------------------------
// Down GEMM, bf16 path: A = h (bf16), B = wd (bf16), global_load_lds staging.
// LDS region: As(8KB) | Bs(8KB). Wave w: insts i=0..3, f=(w*4+i)*64+lane.
// ---------------------------------------------------------------------------
__global__ __launch_bounds__(256, 3) void down_bf_k(
    const unsigned short* __restrict__ h_ws, const unsigned short* __restrict__ wdbf,
    const int* __restrict__ tok_list, const float* __restrict__ w_list,
    const int* __restrict__ n_tot, float* __restrict__ out, int e0) {
    const int ez = blockIdx.z;
    const int e = e0 + ez;
    const int m0 = blockIdx.y * BM;
    if (m0 >= n_tot[e]) return;
    const int n0 = blockIdx.x * BN;

    __shared__ __align__(1024) unsigned short smem[8192];   // 16 KB
    __shared__ int tokL[BM];
    __shared__ float wL[BM];

    const int tid = threadIdx.x, wid = tid >> 6, lane = tid & 63;
    if (tid < BM) {
        tokL[tid] = tok_list[e * CAP2 + m0 + tid];
        wL[tid] = w_list[e * CAP2 + m0 + tid];
    }

    const unsigned short* gsrc[4];
    int ldsoff[4];
#pragma unroll
    for (int i = 0; i < 4; ++i) {
        const int f = (wid * 4 + i) * 64 + lane;
        const unsigned short* g;
        if (f < 512) {
            const int row = f >> 2;
            g = h_ws + ((size_t)ez * CAP2 + m0 + row) * H_DIM + (f & 3) * 8;
        } else {
            const int r = (f - 512) >> 2;
            g = wdbf + ((size_t)e * D_DIM + n0 + r) * H_DIM + (f & 3) * 8;
        }
        gsrc[i] = g;
        ldsoff[i] = (wid * 4 + i) * 1024;
    }

    float4v acc[4][4];
#pragma unroll
    for (int i = 0; i < 4; ++i)
#pragma unroll
        for (int j = 0; j < 4; ++j) acc[i][j] = (float4v){0.f, 0.f, 0.f, 0.f};

    const int wm = (wid & 1) * 64, wn = (wid >> 1) * 64;
    const int frow = lane & 15;
    const int fk = (lane >> 4) * 8;

    for (int k0 = 0; k0 < H_DIM; k0 += BK) {
#pragma unroll
        for (int i = 0; i < 4; ++i)
            __builtin_amdgcn_global_load_lds(
                (gu32*)(gsrc[i] + k0),
                (lu32*)((char*)smem + ldsoff[i]), 16, 0, 0);
        __syncthreads();

        short8 af[4], bf[4];
#pragma unroll
        for (int i = 0; i < 4; ++i)
            af[i] = *(const short8*)&smem[(wm + i * 16 + frow) * 32 + fk];
#pragma unroll
        for (int j = 0; j < 4; ++j)
            bf[j] = *(const short8*)&smem[4096 + (wn + j * 16 + frow) * 32 + fk];
#pragma unroll
        for (int i = 0; i < 4; ++i)
#pragma unroll
            for (int j = 0; j < 4; ++j)
                acc[i][j] = __builtin_amdgcn_mfma_f32_16x16x32_bf16(af[i], bf[j], acc[i][j], 0, 0, 0);
        __syncthreads();
    }

    const int col = lane & 15, rbase = (lane >> 4) * 4;
#pragma unroll
    for (int i = 0; i < 4; ++i)
#pragma unroll
        for (int j = 0; j < 4; ++j)
#pragma unroll
            for (int r = 0; r < 4; ++r) {
                const int m = wm + i * 16 + rbase + r;
                const int n = wn + j * 16 + col;
                const float v = acc[i][j][r] * wL[m];
                unsafeAtomicAdd(&out[(size_t)tokL[m] * D_DIM + n0 + n], v);
            }
}

// ---------------------------------------------------------------------------
// Legacy fp32-staging kernels (fallback if workspace too small for bf16 copies)
// ---------------------------------------------------------------------------
__global__ __launch_bounds__(256, 2) void gateup_legacy_k(
    const float* __restrict__ x,
    const float* __restrict__ wg_all, const float* __restrict__ wu_all,
    const int* __restrict__ tok_list, const int* __restrict__ n_tot,
    unsigned short* __restrict__ h_ws, int e0) {
    const int ez = blockIdx.z;
    const int e = e0 + ez;
    const int m0 = blockIdx.y * BM;
    if (m0 >= n_tot[e]) return;
    const int n0 = blockIdx.x * BN;

    __shared__ __align__(16) unsigned short As[BM][BK];
    __shared__ __align__(16) unsigned short Bg[BN][BK];
    __shared__ __align__(16) unsigned short Bu[BN][BK];
    __shared__ int tokL[BM];

    const int tid = threadIdx.x;
    if (tid < BM) tokL[tid] = tok_list[e * CAP2 + m0 + tid];
    __syncthreads();

    const float* wg = wg_all + (size_t)e * H_DIM * D_DIM;
    const float* wu = wu_all + (size_t)e * H_DIM * D_DIM;

    const float* aSrc[4]; const float* gSrc[4]; const float* uSrc[4];
    unsigned short* aDst[4]; unsigned short* gDst[4]; unsigned short* uDst[4];
#pragma unroll
    for (int it = 0; it < 4; ++it) {
        const int fid = it * 256 + tid;
        const int row = fid >> 3;
        const int c4 = (fid & 7) * 4;
        aSrc[it] = x + (size_t)tokL[row] * D_DIM + c4;
        gSrc[it] = wg + (size_t)(n0 + row) * D_DIM + c4;
        uSrc[it] = wu + (size_t)(n0 + row) * D_DIM + c4;
        aDst[it] = &As[row][c4];
        gDst[it] = &Bg[row][c4];
        uDst[it] = &Bu[row][c4];
    }

    float4v accg[4][4], accu[4][4];
#pragma unroll
    for (int i = 0; i < 4; ++i)
#pragma unroll
        for (int j = 0; j < 4; ++j) {
            accg[i][j] = (float4v){0.f, 0.f, 0.f, 0.f};
            accu[i][j] = (float4v){0.f, 0.f, 0.f, 0.f};
        }

    const int wid = tid >> 6, lane = tid & 63;
    const int wm = (wid & 1) * 64, wn = (wid >> 1) * 64;
    const int frow = lane & 15;
    const int fk = (lane >> 4) * 8;

    for (int k0 = 0; k0 < D_DIM; k0 += BK) {
#pragma unroll
        for (int it = 0; it < 4; ++it) {
            store4bf(aDst[it], *(const float4*)(aSrc[it] + k0));
            store4bf(gDst[it], *(const float4*)(gSrc[it] + k0));
            store4bf(uDst[it], *(const float4*)(uSrc[it] + k0));
        }
        __syncthreads();
        short8 af[4], bgf[4], buf[4];
#pragma unroll
        for (int i = 0; i < 4; ++i)
            af[i] = *(const short8*)&As[wm + i * 16 + frow][fk];
#pragma unroll
        for (int j = 0; j < 4; ++j) {
            bgf[j] = *(const short8*)&Bg[wn + j * 16 + frow][fk];
            buf[j] = *(const short8*)&Bu[wn + j * 16 + frow][fk];
        }
#pragma unroll
        for (int i = 0; i < 4; ++i)
#pragma unroll
            for (int j = 0; j < 4; ++j) {
                accg[i][j] = __builtin_amdgcn_mfma_f32_16x16x32_bf16(af[i], bgf[j], accg[i][j], 0, 0, 0);
                accu[i][j] = __builtin_amdgcn_mfma_f32_16x16x32_bf16(af[i], buf[j], accu[i][j], 0, 0, 0);
            }
        __syncthreads();
    }

    const int col = lane & 15, rbase = (lane >> 4) * 4;
#pragma unroll
    for (int i = 0; i < 4; ++i)
#pragma unroll
        for (int j = 0; j < 4; ++j)
#pragma unroll
            for (int r = 0; r < 4; ++r) {
                const float g = accg[i][j][r];
                const float u = accu[i][j][r];
                const float hv = (g / (1.f + __expf(-g))) * u;
                const int m = wm + i * 16 + rbase + r;
                const int n = wn + j * 16 + col;
                h_ws[((size_t)ez * CAP2 + m0 + m) * H_DIM + (n0 + n)] = f2bf(hv);
            }
}

__global__ __launch_bounds__(256, 2) void down_legacy_k(
    const unsigned short* __restrict__ h_ws, const float* __restrict__ wd_all,
    const int* __restrict__ tok_list, const float* __restrict__ w_list,
    const int* __restrict__ n_tot, float* __restrict__ out, int e0) {
    const int ez = blockIdx.z;
    const int e = e0 + ez;
    const int m0 = blockIdx.y * BM;
    if (m0 >= n_tot[e]) return;
    const int n0 = blockIdx.x * BN;

    __shared__ __align__(16) unsigned short As[BM][BK];
    __shared__ __align__(16) unsigned short Bs[BN][BK];
    __shared__ int tokL[BM];
    __shared__ float wL[BM];

    const int tid = threadIdx.x;
    if (tid < BM) {
        tokL[tid] = tok_list[e * CAP2 + m0 + tid];
        wL[tid] = w_list[e * CAP2 + m0 + tid];
    }
    __syncthreads();

    const unsigned short* hA = h_ws + ((size_t)ez * CAP2 + m0) * H_DIM;
    const float* wd = wd_all + (size_t)e * D_DIM * H_DIM;

    const unsigned short* aSrc[2]; unsigned short* aDst[2];
#pragma unroll
    for (int it = 0; it < 2; ++it) {
        const int fid = it * 256 + tid;
        const int row = fid >> 2;
        const int c8 = (fid & 3) * 8;
        aSrc[it] = hA + (size_t)row * H_DIM + c8;
        aDst[it] = &As[row][c8];
    }
    const float* bSrc[4]; unsigned short* bDst[4];
#pragma unroll
    for (int it = 0; it < 4; ++it) {
        const int fid = it * 256 + tid;
        const int row = fid >> 3;
        const int c4 = (fid & 7) * 4;
        bSrc[it] = wd + (size_t)(n0 + row) * H_DIM + c4;
        bDst[it] = &Bs[row][c4];
    }

    float4v acc[4][4];
#pragma unroll
    for (int i = 0; i < 4; ++i)
#pragma unroll
        for (int j = 0; j < 4; ++j) acc[i][j] = (float4v){0.f, 0.f, 0.f, 0.f};

    const int wid = tid >> 6, lane = tid & 63;
    const int wm = (wid & 1) * 64, wn = (wid >> 1) * 64;
    const int frow = lane & 15;
    const int fk = (lane >> 4) * 8;

    for (int k0 = 0; k0 < H_DIM; k0 += BK) {
#pragma unroll
        for (int it = 0; it < 2; ++it)
            *(uint4*)aDst[it] = *(const uint4*)(aSrc[it] + k0);
#pragma unroll
        for (int it = 0; it < 4; ++it)
            store4bf(bDst[it], *(const float4*)(bSrc[it] + k0));
        __syncthreads();
        short8 af[4], bf[4];
#pragma unroll
        for (int i = 0; i < 4; ++i)
            af[i] = *(const short8*)&As[wm + i * 16 + frow][fk];
#pragma unroll
        for (int j = 0; j < 4; ++j)
            bf[j] = *(const short8*)&Bs[wn + j * 16 + frow][fk];
#pragma unroll
        for (int i = 0; i < 4; ++i)
#pragma unroll
            for (int j = 0; j < 4; ++j)
                acc[i][j] = __builtin_amdgcn_mfma_f32_16x16x32_bf16(af[i], bf[j], acc[i][j], 0, 0, 0);
        __syncthreads();
    }

    const int col = lane & 15, rbase = (lane >> 4) * 4;
#pragma unroll
    for (int i = 0; i < 4; ++i)
#pragma unroll
        for (int j = 0; j < 4; ++j)
#pragma unroll
            for (int r = 0; r < 4; ++r) {
                const int m = wm + i * 16 + rbase + r;
                const int n = wn + j * 16 + col;
                const float v = acc[i][j][r] * wL[m];
                unsafeAtomicAdd(&out[(size_t)tokL[m] * D_DIM + n0 + n], v);
            }
}

// ---------------------------------------------------------------------------
extern "C" void kernel_launch(void* const* d_in, const int* in_sizes, int n_in,
                              void* d_out, int out_size, void* d_ws, size_t ws_size,
                              hipStream_t stream) {
    const float* x        = (const float*)d_in[0];
    const float* gate_w   = (const float*)d_in[1];
    const float* gate_pw  = (const float*)d_in[2];
    const float* up_pw    = (const float*)d_in[3];
    const float* down_pw  = (const float*)d_in[4];
    float* out = (float*)d_out;
    (void)n_in; (void)in_sizes; (void)out_size;

    uint8_t* ws = (uint8_t*)d_ws;
    size_t off = 0;
    int*   topi     = (int*)(ws + off);   off += (size_t)T_TOK * 2 * 4;
    float* topw     = (float*)(ws + off); off += (size_t)T_TOK * 2 * 4;
    int*   tok_list = (int*)(ws + off);   off += (size_t)E_NUM * CAP2 * 4;
    float* w_list   = (float*)(ws + off); off += (size_t)E_NUM * CAP2 * 4;
    int*   n_tot    = (int*)(ws + off);   off += 256;
    off = (off + 4095) & ~(size_t)4095;
    const size_t routing_end = off;

    const size_t x_elems = (size_t)T_TOK * D_DIM;           // 8.4 M
    const size_t w_elems = (size_t)E_NUM * H_DIM * D_DIM;   // 16.8 M each
    unsigned short* xbf  = (unsigned short*)(ws + off); off += x_elems * 2;
    unsigned short* wgbf = (unsigned short*)(ws + off); off += w_elems * 2;
    unsigned short* wubf = (unsigned short*)(ws + off); off += w_elems * 2;
    unsigned short* wdbf = (unsigned short*)(ws + off); off += w_elems * 2;
    const size_t need_base = off;                           // ~118 MB
    const size_t per_e = (size_t)CAP2 * H_DIM * 2;          // 10.5 MB / expert

    hipMemsetAsync(out, 0, (size_t)T_TOK * D_DIM * sizeof(float), stream);
    router_k<<<T_TOK, 64, 0, stream>>>(x, gate_w, topi, topw);
    assign_k<<<1, 1024, 0, stream>>>(topi, topw, tok_list, w_list, n_tot);

    if (ws_size >= need_base + per_e) {
        // bf16 fast path
        unsigned short* h_ws = (unsigned short*)(ws + need_base);
        int chunk = (int)((ws_size - need_base) / per_e);
        if (chunk > E_NUM) chunk = E_NUM;

        const int w4 = (int)(w_elems / 4), x4 = (int)(x_elems / 4);
        convert_k<<<(w4 + 255) / 256, 256, 0, stream>>>(gate_pw, wgbf, w4);
        convert_k<<<(w4 + 255) / 256, 256, 0, stream>>>(up_pw, wubf, w4);
        convert_k<<<(w4 + 255) / 256, 256, 0, stream>>>(down_pw, wdbf, w4);
        convert_k<<<(x4 + 255) / 256, 256, 0, stream>>>(x, xbf, x4);

        for (int e0 = 0; e0 < E_NUM; e0 += chunk) {
            const int ne = (e0 + chunk <= E_NUM) ? chunk : (E_NUM - e0);
            dim3 g1(H_DIM / BN, CAP2 / BM, ne);
            gateup_bf_k<<<g1, 256, 0, stream>>>(xbf, wgbf, wubf, tok_list, n_tot, h_ws, e0);
            dim3 g2(D_DIM / BN, CAP2 / BM, ne);
            down_bf_k<<<g2, 256, 0, stream>>>(h_ws, wdbf, tok_list, w_list, n_tot, out, e0);
        }
    } else {
        // legacy fp32-staging path (small workspace)
        unsigned short* h_ws = (unsigned short*)(ws + routing_end);
        int chunk = (ws_size > routing_end) ? (int)((ws_size - routing_end) / per_e) : 0;
        if (chunk > E_NUM) chunk = E_NUM;
        if (chunk < 1) chunk = 1;

        for (int e0 = 0; e0 < E_NUM; e0 += chunk) {
            const int ne = (e0 + chunk <= E_NUM) ? chunk : (E_NUM - e0);
            dim3 g1(H_DIM / BN, CAP2 / BM, ne);
            gateup_legacy_k<<<g1, 256, 0, stream>>>(x, gate_pw, up_pw, tok_list, n_tot, h_ws, e0);
            dim3 g2(D_DIM / BN, CAP2 / BM, ne);
            down_legacy_k<<<g2, 256, 0, stream>>>(h_ws, down_pw, tok_list, w_list, n_tot, out, e0);
        }
    }
}

// Round 4
// 671.771 us; speedup vs baseline: 1.9133x; 1.0650x over previous
//
#include <hip/hip_runtime.h>
#include <hip/hip_bf16.h>
#include <stdint.h>

// Problem constants (fixed by setup_inputs)
#define T_TOK 8192
#define D_DIM 1024
#define H_DIM 2048
#define E_NUM 8
#define CAP   1280       // int(1.25 * T / E)
#define CAP2  2560       // 2*CAP slots per expert (k=0 block then k=1 block)

#define BM 128
#define BN 128
#define BK 32

typedef __attribute__((ext_vector_type(8))) short short8;   // 8 bf16 (4 VGPRs)
typedef __attribute__((ext_vector_type(4))) float float4v;  // MFMA C/D
typedef __attribute__((address_space(1))) const unsigned int gu32;
typedef __attribute__((address_space(3))) unsigned int lu32;

static __device__ __forceinline__ unsigned short f2bf(float f) {
    unsigned int u = __float_as_uint(f);
    unsigned int r = (u + 0x7FFFu + ((u >> 16) & 1u)) >> 16;  // RNE
    return (unsigned short)r;
}

static __device__ __forceinline__ void store4bf(unsigned short* d, float4 v) {
    union { unsigned short u[4]; uint2 q; } pk;
    pk.u[0] = f2bf(v.x); pk.u[1] = f2bf(v.y);
    pk.u[2] = f2bf(v.z); pk.u[3] = f2bf(v.w);
    *(uint2*)d = pk.q;
}

// ---------------------------------------------------------------------------
// Fused fp32 -> bf16 conversion of all three weight tensors + x (one dispatch)
// ---------------------------------------------------------------------------
__global__ __launch_bounds__(256) void convert_all_k(
    const float* __restrict__ wg, const float* __restrict__ wu,
    const float* __restrict__ wd, const float* __restrict__ x,
    unsigned short* __restrict__ wgbf, unsigned short* __restrict__ wubf,
    unsigned short* __restrict__ wdbf, unsigned short* __restrict__ xbf) {
    const int W4 = E_NUM * H_DIM * D_DIM / 4;   // 4,194,304 float4s per weight
    const int X4 = T_TOK * D_DIM / 4;           // 2,097,152
    const int total = 3 * W4 + X4;
    const int stride = gridDim.x * 256;
    for (int i = blockIdx.x * 256 + threadIdx.x; i < total; i += stride) {
        const float* s; unsigned short* d; int j;
        if (i < W4)            { s = wg; d = wgbf; j = i; }
        else if (i < 2 * W4)   { s = wu; d = wubf; j = i - W4; }
        else if (i < 3 * W4)   { s = wd; d = wdbf; j = i - 2 * W4; }
        else                   { s = x;  d = xbf;  j = i - 3 * W4; }
        store4bf(d + (size_t)j * 4, ((const float4*)s)[j]);
    }
}

// ---------------------------------------------------------------------------
// Router: 4 waves per block, one wave per token.
// ---------------------------------------------------------------------------
__global__ __launch_bounds__(256) void router_k(
    const float* __restrict__ x, const float* __restrict__ gw,
    int* __restrict__ topi, float* __restrict__ topw) {
    const int t = blockIdx.x * 4 + (threadIdx.x >> 6);
    const int lane = threadIdx.x & 63;
    const float* xr = x + (size_t)t * D_DIM;

    float p[E_NUM];
#pragma unroll
    for (int e = 0; e < E_NUM; ++e) p[e] = 0.f;
#pragma unroll
    for (int c = 0; c < 4; ++c) {
        const int idx = c * 256 + lane * 4;
        const float4 xv = *(const float4*)(xr + idx);
#pragma unroll
        for (int e = 0; e < E_NUM; ++e) {
            const float4 gv = *(const float4*)(gw + e * D_DIM + idx);
            p[e] += xv.x * gv.x + xv.y * gv.y + xv.z * gv.z + xv.w * gv.w;
        }
    }
#pragma unroll
    for (int e = 0; e < E_NUM; ++e) {
        float v = p[e];
#pragma unroll
        for (int off = 32; off >= 1; off >>= 1) v += __shfl_xor(v, off);
        p[e] = v;
    }
    if (lane == 0) {
        float mx = p[0];
#pragma unroll
        for (int e = 1; e < E_NUM; ++e) mx = fmaxf(mx, p[e]);
        float pe[E_NUM]; float s = 0.f;
#pragma unroll
        for (int e = 0; e < E_NUM; ++e) { pe[e] = expf(p[e] - mx); s += pe[e]; }
        const float inv = 1.f / s;
        int i0 = 0;
#pragma unroll
        for (int e = 1; e < E_NUM; ++e) if (pe[e] > pe[i0]) i0 = e;
        int i1 = -1;
#pragma unroll
        for (int e = 0; e < E_NUM; ++e) {
            if (e == i0) continue;
            if (i1 < 0 || pe[e] > pe[i1]) i1 = e;
        }
        const float p0 = pe[i0] * inv, p1 = pe[i1] * inv;
        const float wn = 1.f / (p0 + p1 + 1e-9f);
        topi[t * 2 + 0] = i0; topi[t * 2 + 1] = i1;
        topw[t * 2 + 0] = p0 * wn; topw[t * 2 + 1] = p1 * wn;
    }
}

// ---------------------------------------------------------------------------
// Assignment: one block, 16 waves; wave (k,e) scans tokens in order.
// topi staged into LDS as bytes so the serial scans hit LDS, not HBM latency.
// ---------------------------------------------------------------------------
__global__ __launch_bounds__(1024) void assign_k(
    const int* __restrict__ topi, const float* __restrict__ topw,
    int* __restrict__ tok_list, float* __restrict__ w_list,
    int* __restrict__ n_tot) {
    __shared__ unsigned char topiL[T_TOK * 2];   // 16 KB
    __shared__ int kept[2][E_NUM];
    __shared__ int ntotL[E_NUM];
    const int tid = threadIdx.x;
    const int wid = tid >> 6, lane = tid & 63;
    const int k = wid >> 3, e = wid & 7;
    const uint64_t lt = (1ull << lane) - 1ull;

    for (int i = tid; i < T_TOK * 2 / 4; i += 1024) {
        const int4 v = ((const int4*)topi)[i];
        uchar4 b;
        b.x = (unsigned char)v.x; b.y = (unsigned char)v.y;
        b.z = (unsigned char)v.z; b.w = (unsigned char)v.w;
        ((uchar4*)topiL)[i] = b;
    }
    __syncthreads();

    // phase 1: total per-(k,e) counts
    int total = 0;
    for (int base = 0; base < T_TOK; base += 64) {
        const int idx = topiL[(base + lane) * 2 + k];
        total += __popcll(__ballot(idx == e));
    }
    if (lane == 0) kept[k][e] = min(total, CAP);
    __syncthreads();
    if (tid < E_NUM) {
        ntotL[tid] = kept[0][tid] + kept[1][tid];
        n_tot[tid] = ntotL[tid];
    }
    const int myBase = e * CAP2 + (k ? kept[0][e] : 0);

    // phase 2: ordered compaction of kept tokens
    int running = 0, keptRun = 0;
    for (int base = 0; base < T_TOK; base += 64) {
        const int t = base + lane;
        const bool pred = (topiL[t * 2 + k] == e);
        const uint64_t m = __ballot(pred);
        const int rank = running + __popcll(m & lt);
        const bool keep = pred && (rank < CAP);
        const uint64_t km = __ballot(keep);
        if (keep) {
            const int slot = myBase + keptRun + __popcll(km & lt);
            tok_list[slot] = t;
            w_list[slot] = topw[t * 2 + k];
        }
        running += __popcll(m);
        keptRun += __popcll(km);
    }
    __syncthreads();
    // phase 3: pad unused slots (safe token 0, zero weight)
    for (int s = tid; s < E_NUM * CAP2; s += 1024) {
        const int ee = s / CAP2, ls = s - ee * CAP2;
        if (ls >= ntotL[ee]) { tok_list[s] = 0; w_list[s] = 0.f; }
    }
}

// ---------------------------------------------------------------------------
// Fused gate+up GEMM, bf16 path (UNCHANGED from round 3 — control).
// ---------------------------------------------------------------------------
__global__ __launch_bounds__(256, 2) void gateup_bf_k(
    const unsigned short* __restrict__ xbf,
    const unsigned short* __restrict__ wgbf, const unsigned short* __restrict__ wubf,
    const int* __restrict__ tok_list, const int* __restrict__ n_tot,
    unsigned short* __restrict__ h_ws, int e0) {
    const int ez = blockIdx.z;
    const int e = e0 + ez;
    const int m0 = blockIdx.y * BM;
    if (m0 >= n_tot[e]) return;
    const int n0 = blockIdx.x * BN;

    __shared__ __align__(1024) unsigned short smem[12288];   // 24 KB

    const int tid = threadIdx.x, wid = tid >> 6, lane = tid & 63;

    const unsigned short* gsrc[6];
    int ldsoff[6];
#pragma unroll
    for (int i = 0; i < 6; ++i) {
        const int f = (wid * 6 + i) * 64 + lane;
        const unsigned short* g;
        if (f < 512) {
            const int row = f >> 2;
            const int tok = tok_list[e * CAP2 + m0 + row];
            g = xbf + (size_t)tok * D_DIM + (f & 3) * 8;
        } else if (f < 1024) {
            const int r = (f - 512) >> 2;
            g = wgbf + ((size_t)e * H_DIM + n0 + r) * D_DIM + (f & 3) * 8;
        } else {
            const int r = (f - 1024) >> 2;
            g = wubf + ((size_t)e * H_DIM + n0 + r) * D_DIM + (f & 3) * 8;
        }
        gsrc[i] = g;
        ldsoff[i] = (wid * 6 + i) * 1024;   // bytes, wave-uniform
    }

    float4v accg[4][4], accu[4][4];
#pragma unroll
    for (int i = 0; i < 4; ++i)
#pragma unroll
        for (int j = 0; j < 4; ++j) {
            accg[i][j] = (float4v){0.f, 0.f, 0.f, 0.f};
            accu[i][j] = (float4v){0.f, 0.f, 0.f, 0.f};
        }

    const int wm = (wid & 1) * 64, wn = (wid >> 1) * 64;
    const int frow = lane & 15;
    const int fk = (lane >> 4) * 8;

    for (int k0 = 0; k0 < D_DIM; k0 += BK) {
#pragma unroll
        for (int i = 0; i < 6; ++i)
            __builtin_amdgcn_global_load_lds(
                (gu32*)(gsrc[i] + k0),
                (lu32*)((char*)smem + ldsoff[i]), 16, 0, 0);
        __syncthreads();

        short8 af[4], bgf[4], buf[4];
#pragma unroll
        for (int i = 0; i < 4; ++i)
            af[i] = *(const short8*)&smem[(wm + i * 16 + frow) * 32 + fk];
#pragma unroll
        for (int j = 0; j < 4; ++j) {
            bgf[j] = *(const short8*)&smem[4096 + (wn + j * 16 + frow) * 32 + fk];
            buf[j] = *(const short8*)&smem[8192 + (wn + j * 16 + frow) * 32 + fk];
        }
#pragma unroll
        for (int i = 0; i < 4; ++i)
#pragma unroll
            for (int j = 0; j < 4; ++j) {
                accg[i][j] = __builtin_amdgcn_mfma_f32_16x16x32_bf16(af[i], bgf[j], accg[i][j], 0, 0, 0);
                accu[i][j] = __builtin_amdgcn_mfma_f32_16x16x32_bf16(af[i], buf[j], accu[i][j], 0, 0, 0);
            }
        __syncthreads();
    }

    const int col = lane & 15, rbase = (lane >> 4) * 4;
#pragma unroll
    for (int i = 0; i < 4; ++i)
#pragma unroll
        for (int j = 0; j < 4; ++j)
#pragma unroll
            for (int r = 0; r < 4; ++r) {
                const float g = accg[i][j][r];
                const float u = accu[i][j][r];
                const float hv = (g / (1.f + __expf(-g))) * u;
                const int m = wm + i * 16 + rbase + r;
                const int n = wn + j * 16 + col;
                h_ws[((size_t)ez * CAP2 + m0 + m) * H_DIM + (n0 + n)] = f2bf(hv);
            }
}

// ---------------------------------------------------------------------------
// Down GEMM, bf16: BK=64 (half the barriers, gateup-density MFMA/iter) with
// XOR chunk swizzle. LDS slot (16B) for (row r, chunk c) = r*8 + (c ^ (r&7));
// frag ds_read_b128 then lands 2 lanes/bank (conflict-free, m136), while the
// global side stays a permutation within 128B lines (coalescing preserved).
// global_load_lds forbids padding (m104/m108) — swizzle is the workaround.
// ---------------------------------------------------------------------------
__global__ __launch_bounds__(256, 2) void down_bf_k(
    const unsigned short* __restrict__ h_ws, const unsigned short* __restrict__ wdbf,
    const int* __restrict__ tok_list, const float* __restrict__ w_list,
    const int* __restrict__ n_tot, float* __restrict__ out, int e0) {
    const int ez = blockIdx.z;
    const int e = e0 + ez;
    const int m0 = blockIdx.y * BM;
    if (m0 >= n_tot[e]) return;
    const int n0 = blockIdx.x * BN;

    __shared__ __align__(1024) unsigned short smem[16384];   // 32 KB: A|B
    __shared__ int tokL[BM];
    __shared__ float wL[BM];

    const int tid = threadIdx.x, wid = tid >> 6, lane = tid & 63;
    if (tid < BM) {
        tokL[tid] = tok_list[e * CAP2 + m0 + tid];
        wL[tid] = w_list[e * CAP2 + m0 + tid];
    }

    const unsigned short* gsrc[8];
    int ldsoff[8];
#pragma unroll
    for (int i = 0; i < 8; ++i) {
        const int f = (wid * 8 + i) * 64 + lane;   // 16B slot index, 0..2047
        const unsigned short* g;
        if (f < 1024) {          // A region: h rows, 128 rows x 8 chunks
            const int r = f >> 3, c = (f & 7) ^ (r & 7);
            g = h_ws + ((size_t)ez * CAP2 + m0 + r) * H_DIM + c * 8;
        } else {                 // B region: wd rows
            const int fr = f - 1024;
            const int r = fr >> 3, c = (fr & 7) ^ (r & 7);
            g = wdbf + ((size_t)e * D_DIM + n0 + r) * H_DIM + c * 8;
        }
        gsrc[i] = g;
        ldsoff[i] = (wid * 8 + i) * 1024;   // bytes, wave-uniform
    }

    float4v acc[4][4];
#pragma unroll
    for (int i = 0; i < 4; ++i)
#pragma unroll
        for (int j = 0; j < 4; ++j) acc[i][j] = (float4v){0.f, 0.f, 0.f, 0.f};

    const int wm = (wid & 1) * 64, wn = (wid >> 1) * 64;
    const int frow = lane & 15;
    const int quad = lane >> 4;

    for (int k0 = 0; k0 < H_DIM; k0 += 64) {
#pragma unroll
        for (int i = 0; i < 8; ++i)
            __builtin_amdgcn_global_load_lds(
                (gu32*)(gsrc[i] + k0),
                (lu32*)((char*)smem + ldsoff[i]), 16, 0, 0);
        __syncthreads();

        short8 af[2][4], bf[2][4];
#pragma unroll
        for (int s = 0; s < 2; ++s) {
            const int c = s * 4 + quad;
#pragma unroll
            for (int i = 0; i < 4; ++i) {
                const int row = wm + i * 16 + frow;
                af[s][i] = *(const short8*)&smem[(row * 8 + (c ^ (row & 7))) * 8];
            }
#pragma unroll
            for (int j = 0; j < 4; ++j) {
                const int row = wn + j * 16 + frow;
                bf[s][j] = *(const short8*)&smem[8192 + (row * 8 + (c ^ (row & 7))) * 8];
            }
        }
#pragma unroll
        for (int s = 0; s < 2; ++s)
#pragma unroll
            for (int i = 0; i < 4; ++i)
#pragma unroll
                for (int j = 0; j < 4; ++j)
                    acc[i][j] = __builtin_amdgcn_mfma_f32_16x16x32_bf16(af[s][i], bf[s][j], acc[i][j], 0, 0, 0);
        __syncthreads();
    }

    const int col = lane & 15, rbase = (lane >> 4) * 4;
#pragma unroll
    for (int i = 0; i < 4; ++i)
#pragma unroll
        for (int j = 0; j < 4; ++j)
#pragma unroll
            for (int r = 0; r < 4; ++r) {
                const int m = wm + i * 16 + rbase + r;
                const int n = wn + j * 16 + col;
                const float v = acc[i][j][r] * wL[m];
                unsafeAtomicAdd(&out[(size_t)tokL[m] * D_DIM + n0 + n], v);
            }
}

// ---------------------------------------------------------------------------
// Legacy fp32-staging kernels (fallback if workspace too small for bf16 copies)
// ---------------------------------------------------------------------------
__global__ __launch_bounds__(256, 2) void gateup_legacy_k(
    const float* __restrict__ x,
    const float* __restrict__ wg_all, const float* __restrict__ wu_all,
    const int* __restrict__ tok_list, const int* __restrict__ n_tot,
    unsigned short* __restrict__ h_ws, int e0) {
    const int ez = blockIdx.z;
    const int e = e0 + ez;
    const int m0 = blockIdx.y * BM;
    if (m0 >= n_tot[e]) return;
    const int n0 = blockIdx.x * BN;

    __shared__ __align__(16) unsigned short As[BM][BK];
    __shared__ __align__(16) unsigned short Bg[BN][BK];
    __shared__ __align__(16) unsigned short Bu[BN][BK];
    __shared__ int tokL[BM];

    const int tid = threadIdx.x;
    if (tid < BM) tokL[tid] = tok_list[e * CAP2 + m0 + tid];
    __syncthreads();

    const float* wg = wg_all + (size_t)e * H_DIM * D_DIM;
    const float* wu = wu_all + (size_t)e * H_DIM * D_DIM;

    const float* aSrc[4]; const float* gSrc[4]; const float* uSrc[4];
    unsigned short* aDst[4]; unsigned short* gDst[4]; unsigned short* uDst[4];
#pragma unroll
    for (int it = 0; it < 4; ++it) {
        const int fid = it * 256 + tid;
        const int row = fid >> 3;
        const int c4 = (fid & 7) * 4;
        aSrc[it] = x + (size_t)tokL[row] * D_DIM + c4;
        gSrc[it] = wg + (size_t)(n0 + row) * D_DIM + c4;
        uSrc[it] = wu + (size_t)(n0 + row) * D_DIM + c4;
        aDst[it] = &As[row][c4];
        gDst[it] = &Bg[row][c4];
        uDst[it] = &Bu[row][c4];
    }

    float4v accg[4][4], accu[4][4];
#pragma unroll
    for (int i = 0; i < 4; ++i)
#pragma unroll
        for (int j = 0; j < 4; ++j) {
            accg[i][j] = (float4v){0.f, 0.f, 0.f, 0.f};
            accu[i][j] = (float4v){0.f, 0.f, 0.f, 0.f};
        }

    const int wid = tid >> 6, lane = tid & 63;
    const int wm = (wid & 1) * 64, wn = (wid >> 1) * 64;
    const int frow = lane & 15;
    const int fk = (lane >> 4) * 8;

    for (int k0 = 0; k0 < D_DIM; k0 += BK) {
#pragma unroll
        for (int it = 0; it < 4; ++it) {
            store4bf(aDst[it], *(const float4*)(aSrc[it] + k0));
            store4bf(gDst[it], *(const float4*)(gSrc[it] + k0));
            store4bf(uDst[it], *(const float4*)(uSrc[it] + k0));
        }
        __syncthreads();
        short8 af[4], bgf[4], buf[4];
#pragma unroll
        for (int i = 0; i < 4; ++i)
            af[i] = *(const short8*)&As[wm + i * 16 + frow][fk];
#pragma unroll
        for (int j = 0; j < 4; ++j) {
            bgf[j] = *(const short8*)&Bg[wn + j * 16 + frow][fk];
            buf[j] = *(const short8*)&Bu[wn + j * 16 + frow][fk];
        }
#pragma unroll
        for (int i = 0; i < 4; ++i)
#pragma unroll
            for (int j = 0; j < 4; ++j) {
                accg[i][j] = __builtin_amdgcn_mfma_f32_16x16x32_bf16(af[i], bgf[j], accg[i][j], 0, 0, 0);
                accu[i][j] = __builtin_amdgcn_mfma_f32_16x16x32_bf16(af[i], buf[j], accu[i][j], 0, 0, 0);
            }
        __syncthreads();
    }

    const int col = lane & 15, rbase = (lane >> 4) * 4;
#pragma unroll
    for (int i = 0; i < 4; ++i)
#pragma unroll
        for (int j = 0; j < 4; ++j)
#pragma unroll
            for (int r = 0; r < 4; ++r) {
                const float g = accg[i][j][r];
                const float u = accu[i][j][r];
                const float hv = (g / (1.f + __expf(-g))) * u;
                const int m = wm + i * 16 + rbase + r;
                const int n = wn + j * 16 + col;
                h_ws[((size_t)ez * CAP2 + m0 + m) * H_DIM + (n0 + n)] = f2bf(hv);
            }
}

__global__ __launch_bounds__(256, 2) void down_legacy_k(
    const unsigned short* __restrict__ h_ws, const float* __restrict__ wd_all,
    const int* __restrict__ tok_list, const float* __restrict__ w_list,
    const int* __restrict__ n_tot, float* __restrict__ out, int e0) {
    const int ez = blockIdx.z;
    const int e = e0 + ez;
    const int m0 = blockIdx.y * BM;
    if (m0 >= n_tot[e]) return;
    const int n0 = blockIdx.x * BN;

    __shared__ __align__(16) unsigned short As[BM][BK];
    __shared__ __align__(16) unsigned short Bs[BN][BK];
    __shared__ int tokL[BM];
    __shared__ float wL[BM];

    const int tid = threadIdx.x;
    if (tid < BM) {
        tokL[tid] = tok_list[e * CAP2 + m0 + tid];
        wL[tid] = w_list[e * CAP2 + m0 + tid];
    }
    __syncthreads();

    const unsigned short* hA = h_ws + ((size_t)ez * CAP2 + m0) * H_DIM;
    const float* wd = wd_all + (size_t)e * D_DIM * H_DIM;

    const unsigned short* aSrc[2]; unsigned short* aDst[2];
#pragma unroll
    for (int it = 0; it < 2; ++it) {
        const int fid = it * 256 + tid;
        const int row = fid >> 2;
        const int c8 = (fid & 3) * 8;
        aSrc[it] = hA + (size_t)row * H_DIM + c8;
        aDst[it] = &As[row][c8];
    }
    const float* bSrc[4]; unsigned short* bDst[4];
#pragma unroll
    for (int it = 0; it < 4; ++it) {
        const int fid = it * 256 + tid;
        const int row = fid >> 3;
        const int c4 = (fid & 7) * 4;
        bSrc[it] = wd + (size_t)(n0 + row) * H_DIM + c4;
        bDst[it] = &Bs[row][c4];
    }

    float4v acc[4][4];
#pragma unroll
    for (int i = 0; i < 4; ++i)
#pragma unroll
        for (int j = 0; j < 4; ++j) acc[i][j] = (float4v){0.f, 0.f, 0.f, 0.f};

    const int wid = tid >> 6, lane = tid & 63;
    const int wm = (wid & 1) * 64, wn = (wid >> 1) * 64;
    const int frow = lane & 15;
    const int fk = (lane >> 4) * 8;

    for (int k0 = 0; k0 < H_DIM; k0 += BK) {
#pragma unroll
        for (int it = 0; it < 2; ++it)
            *(uint4*)aDst[it] = *(const uint4*)(aSrc[it] + k0);
#pragma unroll
        for (int it = 0; it < 4; ++it)
            store4bf(bDst[it], *(const float4*)(bSrc[it] + k0));
        __syncthreads();
        short8 af[4], bf[4];
#pragma unroll
        for (int i = 0; i < 4; ++i)
            af[i] = *(const short8*)&As[wm + i * 16 + frow][fk];
#pragma unroll
        for (int j = 0; j < 4; ++j)
            bf[j] = *(const short8*)&Bs[wn + j * 16 + frow][fk];
#pragma unroll
        for (int i = 0; i < 4; ++i)
#pragma unroll
            for (int j = 0; j < 4; ++j)
                acc[i][j] = __builtin_amdgcn_mfma_f32_16x16x32_bf16(af[i], bf[j], acc[i][j], 0, 0, 0);
        __syncthreads();
    }

    const int col = lane & 15, rbase = (lane >> 4) * 4;
#pragma unroll
    for (int i = 0; i < 4; ++i)
#pragma unroll
        for (int j = 0; j < 4; ++j)
#pragma unroll
            for (int r = 0; r < 4; ++r) {
                const int m = wm + i * 16 + rbase + r;
                const int n = wn + j * 16 + col;
                const float v = acc[i][j][r] * wL[m];
                unsafeAtomicAdd(&out[(size_t)tokL[m] * D_DIM + n0 + n], v);
            }
}

// ---------------------------------------------------------------------------
extern "C" void kernel_launch(void* const* d_in, const int* in_sizes, int n_in,
                              void* d_out, int out_size, void* d_ws, size_t ws_size,
                              hipStream_t stream) {
    const float* x        = (const float*)d_in[0];
    const float* gate_w   = (const float*)d_in[1];
    const float* gate_pw  = (const float*)d_in[2];
    const float* up_pw    = (const float*)d_in[3];
    const float* down_pw  = (const float*)d_in[4];
    float* out = (float*)d_out;
    (void)n_in; (void)in_sizes; (void)out_size;

    uint8_t* ws = (uint8_t*)d_ws;
    size_t off = 0;
    int*   topi     = (int*)(ws + off);   off += (size_t)T_TOK * 2 * 4;
    float* topw     = (float*)(ws + off); off += (size_t)T_TOK * 2 * 4;
    int*   tok_list = (int*)(ws + off);   off += (size_t)E_NUM * CAP2 * 4;
    float* w_list   = (float*)(ws + off); off += (size_t)E_NUM * CAP2 * 4;
    int*   n_tot    = (int*)(ws + off);   off += 256;
    off = (off + 4095) & ~(size_t)4095;
    const size_t routing_end = off;

    const size_t x_elems = (size_t)T_TOK * D_DIM;           // 8.4 M
    const size_t w_elems = (size_t)E_NUM * H_DIM * D_DIM;   // 16.8 M each
    unsigned short* xbf  = (unsigned short*)(ws + off); off += x_elems * 2;
    unsigned short* wgbf = (unsigned short*)(ws + off); off += w_elems * 2;
    unsigned short* wubf = (unsigned short*)(ws + off); off += w_elems * 2;
    unsigned short* wdbf = (unsigned short*)(ws + off); off += w_elems * 2;
    const size_t need_base = off;                           // ~118 MB
    const size_t per_e = (size_t)CAP2 * H_DIM * 2;          // 10.5 MB / expert

    hipMemsetAsync(out, 0, (size_t)T_TOK * D_DIM * sizeof(float), stream);
    router_k<<<T_TOK / 4, 256, 0, stream>>>(x, gate_w, topi, topw);
    assign_k<<<1, 1024, 0, stream>>>(topi, topw, tok_list, w_list, n_tot);

    if (ws_size >= need_base + per_e) {
        // bf16 fast path
        unsigned short* h_ws = (unsigned short*)(ws + need_base);
        int chunk = (int)((ws_size - need_base) / per_e);
        if (chunk > E_NUM) chunk = E_NUM;

        convert_all_k<<<4096, 256, 0, stream>>>(gate_pw, up_pw, down_pw, x,
                                                wgbf, wubf, wdbf, xbf);

        for (int e0 = 0; e0 < E_NUM; e0 += chunk) {
            const int ne = (e0 + chunk <= E_NUM) ? chunk : (E_NUM - e0);
            dim3 g1(H_DIM / BN, CAP2 / BM, ne);
            gateup_bf_k<<<g1, 256, 0, stream>>>(xbf, wgbf, wubf, tok_list, n_tot, h_ws, e0);
            dim3 g2(D_DIM / BN, CAP2 / BM, ne);
            down_bf_k<<<g2, 256, 0, stream>>>(h_ws, wdbf, tok_list, w_list, n_tot, out, e0);
        }
    } else {
        // legacy fp32-staging path (small workspace)
        unsigned short* h_ws = (unsigned short*)(ws + routing_end);
        int chunk = (ws_size > routing_end) ? (int)((ws_size - routing_end) / per_e) : 0;
        if (chunk > E_NUM) chunk = E_NUM;
        if (chunk < 1) chunk = 1;

        for (int e0 = 0; e0 < E_NUM; e0 += chunk) {
            const int ne = (e0 + chunk <= E_NUM) ? chunk : (E_NUM - e0);
            dim3 g1(H_DIM / BN, CAP2 / BM, ne);
            gateup_legacy_k<<<g1, 256, 0, stream>>>(x, gate_pw, up_pw, tok_list, n_tot, h_ws, e0);
            dim3 g2(D_DIM / BN, CAP2 / BM, ne);
            down_legacy_k<<<g2, 256, 0, stream>>>(h_ws, down_pw, tok_list, w_list, n_tot, out, e0);
        }
    }
}

// Round 5
// 639.770 us; speedup vs baseline: 2.0090x; 1.0500x over previous
//
#include <hip/hip_runtime.h>
#include <hip/hip_bf16.h>
#include <stdint.h>

// Problem constants (fixed by setup_inputs)
#define T_TOK 8192
#define D_DIM 1024
#define H_DIM 2048
#define E_NUM 8
#define CAP   1280       // int(1.25 * T / E)
#define CAP2  2560       // per expert: [k=0: CAP slots][k=1: CAP slots]
#define MT_K  10         // M-tiles per (e,k) region: CAP/BM

#define BM 128
#define BN 128
#define BK 32

typedef __attribute__((ext_vector_type(8))) short short8;   // 8 bf16 (4 VGPRs)
typedef __attribute__((ext_vector_type(4))) float float4v;  // MFMA C/D
typedef __attribute__((address_space(1))) const unsigned int gu32;
typedef __attribute__((address_space(3))) unsigned int lu32;

static __device__ __forceinline__ unsigned short f2bf(float f) {
    unsigned int u = __float_as_uint(f);
    unsigned int r = (u + 0x7FFFu + ((u >> 16) & 1u)) >> 16;  // RNE
    return (unsigned short)r;
}

static __device__ __forceinline__ void store4bf(unsigned short* d, float4 v) {
    union { unsigned short u[4]; uint2 q; } pk;
    pk.u[0] = f2bf(v.x); pk.u[1] = f2bf(v.y);
    pk.u[2] = f2bf(v.z); pk.u[3] = f2bf(v.w);
    *(uint2*)d = pk.q;
}

// ---------------------------------------------------------------------------
// fp32 -> bf16 conversion of the three weight tensors (x handled in router)
// ---------------------------------------------------------------------------
__global__ __launch_bounds__(256) void convert_w_k(
    const float* __restrict__ wg, const float* __restrict__ wu,
    const float* __restrict__ wd,
    unsigned short* __restrict__ wgbf, unsigned short* __restrict__ wubf,
    unsigned short* __restrict__ wdbf) {
    const int W4 = E_NUM * H_DIM * D_DIM / 4;   // 4,194,304 float4s per weight
    const int total = 3 * W4;
    const int stride = gridDim.x * 256;
    for (int i = blockIdx.x * 256 + threadIdx.x; i < total; i += stride) {
        const float* s; unsigned short* d; int j;
        if (i < W4)          { s = wg; d = wgbf; j = i; }
        else if (i < 2 * W4) { s = wu; d = wubf; j = i - W4; }
        else                 { s = wd; d = wdbf; j = i - 2 * W4; }
        store4bf(d + (size_t)j * 4, ((const float4*)s)[j]);
    }
}

// ---------------------------------------------------------------------------
// Router: 4 waves/block, one wave per token. Also converts x -> bf16 (row is
// already in registers).
// ---------------------------------------------------------------------------
__global__ __launch_bounds__(256) void router_k(
    const float* __restrict__ x, const float* __restrict__ gw,
    int* __restrict__ topi, float* __restrict__ topw,
    unsigned short* __restrict__ xbf) {
    const int t = blockIdx.x * 4 + (threadIdx.x >> 6);
    const int lane = threadIdx.x & 63;
    const float* xr = x + (size_t)t * D_DIM;
    unsigned short* xbr = xbf + (size_t)t * D_DIM;

    float p[E_NUM];
#pragma unroll
    for (int e = 0; e < E_NUM; ++e) p[e] = 0.f;
#pragma unroll
    for (int c = 0; c < 4; ++c) {
        const int idx = c * 256 + lane * 4;
        const float4 xv = *(const float4*)(xr + idx);
        store4bf(xbr + idx, xv);
#pragma unroll
        for (int e = 0; e < E_NUM; ++e) {
            const float4 gv = *(const float4*)(gw + e * D_DIM + idx);
            p[e] += xv.x * gv.x + xv.y * gv.y + xv.z * gv.z + xv.w * gv.w;
        }
    }
#pragma unroll
    for (int e = 0; e < E_NUM; ++e) {
        float v = p[e];
#pragma unroll
        for (int off = 32; off >= 1; off >>= 1) v += __shfl_xor(v, off);
        p[e] = v;
    }
    if (lane == 0) {
        float mx = p[0];
#pragma unroll
        for (int e = 1; e < E_NUM; ++e) mx = fmaxf(mx, p[e]);
        float pe[E_NUM]; float s = 0.f;
#pragma unroll
        for (int e = 0; e < E_NUM; ++e) { pe[e] = expf(p[e] - mx); s += pe[e]; }
        const float inv = 1.f / s;
        int i0 = 0;
#pragma unroll
        for (int e = 1; e < E_NUM; ++e) if (pe[e] > pe[i0]) i0 = e;
        int i1 = -1;
#pragma unroll
        for (int e = 0; e < E_NUM; ++e) {
            if (e == i0) continue;
            if (i1 < 0 || pe[e] > pe[i1]) i1 = e;
        }
        const float p0 = pe[i0] * inv, p1 = pe[i1] * inv;
        const float wn = 1.f / (p0 + p1 + 1e-9f);
        topi[t * 2 + 0] = i0; topi[t * 2 + 1] = i1;
        topw[t * 2 + 0] = p0 * wn; topw[t * 2 + 1] = p1 * wn;
    }
}

// ---------------------------------------------------------------------------
// Assignment: one block, 16 waves; wave (k,e) scans tokens in order.
// NEW layout: expert e slots = [k=0: e*CAP2 + 0..CAP) [k=1: e*CAP2+CAP ..).
// cnt[e*2+k] = kept count per (e,k). Pad slots: tok=0, w=0 (masked in down).
// ---------------------------------------------------------------------------
__global__ __launch_bounds__(1024) void assign_k(
    const int* __restrict__ topi, const float* __restrict__ topw,
    int* __restrict__ tok_list, float* __restrict__ w_list,
    int* __restrict__ cnt) {
    __shared__ unsigned char topiL[T_TOK * 2];   // 16 KB
    __shared__ int kept[2][E_NUM];
    const int tid = threadIdx.x;
    const int wid = tid >> 6, lane = tid & 63;
    const int k = wid >> 3, e = wid & 7;
    const uint64_t lt = (1ull << lane) - 1ull;

    for (int i = tid; i < T_TOK * 2 / 4; i += 1024) {
        const int4 v = ((const int4*)topi)[i];
        uchar4 b;
        b.x = (unsigned char)v.x; b.y = (unsigned char)v.y;
        b.z = (unsigned char)v.z; b.w = (unsigned char)v.w;
        ((uchar4*)topiL)[i] = b;
    }
    __syncthreads();

    // phase 1: total per-(k,e) counts
    int total = 0;
    for (int base = 0; base < T_TOK; base += 64) {
        const int idx = topiL[(base + lane) * 2 + k];
        total += __popcll(__ballot(idx == e));
    }
    if (lane == 0) {
        const int kc = min(total, CAP);
        kept[k][e] = kc;
        cnt[e * 2 + k] = kc;
    }
    __syncthreads();
    const int myBase = e * CAP2 + k * CAP;

    // phase 2: ordered compaction of kept tokens
    int running = 0, keptRun = 0;
    for (int base = 0; base < T_TOK; base += 64) {
        const int t = base + lane;
        const bool pred = (topiL[t * 2 + k] == e);
        const uint64_t m = __ballot(pred);
        const int rank = running + __popcll(m & lt);
        const bool keep = pred && (rank < CAP);
        const uint64_t km = __ballot(keep);
        if (keep) {
            const int slot = myBase + keptRun + __popcll(km & lt);
            tok_list[slot] = t;
            w_list[slot] = topw[t * 2 + k];
        }
        running += __popcll(m);
        keptRun += __popcll(km);
    }
    __syncthreads();
    // phase 3: pad unused slots (safe token 0, zero weight)
    for (int s = tid; s < E_NUM * CAP2; s += 1024) {
        const int ee = s / CAP2;
        const int rem = s - ee * CAP2;
        const int kk = rem / CAP, ls = rem - kk * CAP;
        if (ls >= kept[kk][ee]) { tok_list[s] = 0; w_list[s] = 0.f; }
    }
}

// ---------------------------------------------------------------------------
// Fused gate+up GEMM, bf16 (structure unchanged — control). blockIdx.y in
// [0,20): region kk = y/10, tile m0 = (y%10)*BM inside the (e,kk) region.
// ---------------------------------------------------------------------------
__global__ __launch_bounds__(256, 2) void gateup_bf_k(
    const unsigned short* __restrict__ xbf,
    const unsigned short* __restrict__ wgbf, const unsigned short* __restrict__ wubf,
    const int* __restrict__ tok_list, const int* __restrict__ cnt,
    unsigned short* __restrict__ h_ws, int e0) {
    const int ez = blockIdx.z;
    const int e = e0 + ez;
    const int kk = blockIdx.y / MT_K;
    const int m0 = (blockIdx.y - kk * MT_K) * BM;
    if (m0 >= cnt[e * 2 + kk]) return;
    const int n0 = blockIdx.x * BN;
    const int sbase = e * CAP2 + kk * CAP + m0;           // global slot base
    const size_t hbase = (size_t)ez * CAP2 + kk * CAP + m0;

    __shared__ __align__(1024) unsigned short smem[12288];   // 24 KB

    const int tid = threadIdx.x, wid = tid >> 6, lane = tid & 63;

    const unsigned short* gsrc[6];
    int ldsoff[6];
#pragma unroll
    for (int i = 0; i < 6; ++i) {
        const int f = (wid * 6 + i) * 64 + lane;
        const unsigned short* g;
        if (f < 512) {
            const int row = f >> 2;
            const int tok = tok_list[sbase + row];
            g = xbf + (size_t)tok * D_DIM + (f & 3) * 8;
        } else if (f < 1024) {
            const int r = (f - 512) >> 2;
            g = wgbf + ((size_t)e * H_DIM + n0 + r) * D_DIM + (f & 3) * 8;
        } else {
            const int r = (f - 1024) >> 2;
            g = wubf + ((size_t)e * H_DIM + n0 + r) * D_DIM + (f & 3) * 8;
        }
        gsrc[i] = g;
        ldsoff[i] = (wid * 6 + i) * 1024;   // bytes, wave-uniform
    }

    float4v accg[4][4], accu[4][4];
#pragma unroll
    for (int i = 0; i < 4; ++i)
#pragma unroll
        for (int j = 0; j < 4; ++j) {
            accg[i][j] = (float4v){0.f, 0.f, 0.f, 0.f};
            accu[i][j] = (float4v){0.f, 0.f, 0.f, 0.f};
        }

    const int wm = (wid & 1) * 64, wn = (wid >> 1) * 64;
    const int frow = lane & 15;
    const int fk = (lane >> 4) * 8;

    for (int k0 = 0; k0 < D_DIM; k0 += BK) {
#pragma unroll
        for (int i = 0; i < 6; ++i)
            __builtin_amdgcn_global_load_lds(
                (gu32*)(gsrc[i] + k0),
                (lu32*)((char*)smem + ldsoff[i]), 16, 0, 0);
        __syncthreads();

        short8 af[4], bgf[4], buf[4];
#pragma unroll
        for (int i = 0; i < 4; ++i)
            af[i] = *(const short8*)&smem[(wm + i * 16 + frow) * 32 + fk];
#pragma unroll
        for (int j = 0; j < 4; ++j) {
            bgf[j] = *(const short8*)&smem[4096 + (wn + j * 16 + frow) * 32 + fk];
            buf[j] = *(const short8*)&smem[8192 + (wn + j * 16 + frow) * 32 + fk];
        }
#pragma unroll
        for (int i = 0; i < 4; ++i)
#pragma unroll
            for (int j = 0; j < 4; ++j) {
                accg[i][j] = __builtin_amdgcn_mfma_f32_16x16x32_bf16(af[i], bgf[j], accg[i][j], 0, 0, 0);
                accu[i][j] = __builtin_amdgcn_mfma_f32_16x16x32_bf16(af[i], buf[j], accu[i][j], 0, 0, 0);
            }
        __syncthreads();
    }

    const int col = lane & 15, rbase = (lane >> 4) * 4;
#pragma unroll
    for (int i = 0; i < 4; ++i)
#pragma unroll
        for (int j = 0; j < 4; ++j)
#pragma unroll
            for (int r = 0; r < 4; ++r) {
                const float g = accg[i][j][r];
                const float u = accu[i][j][r];
                const float hv = (g / (1.f + __expf(-g))) * u;
                const int m = wm + i * 16 + rbase + r;
                const int n = wn + j * 16 + col;
                h_ws[(hbase + m) * H_DIM + (n0 + n)] = f2bf(hv);
            }
}

// ---------------------------------------------------------------------------
// Down GEMM pass (one k at a time) — NO ATOMICS. Pass kk=0: plain stores
// (memset covers dropped rows). Pass kk=1: load-add-store. Pad rows masked.
// BK=64 with XOR chunk swizzle (global_load_lds forbids padding, m104/m108).
// ---------------------------------------------------------------------------
__global__ __launch_bounds__(256, 2) void down_bf_k(
    const unsigned short* __restrict__ h_ws, const unsigned short* __restrict__ wdbf,
    const int* __restrict__ tok_list, const float* __restrict__ w_list,
    const int* __restrict__ cnt, float* __restrict__ out, int e0, int kk) {
    const int ez = blockIdx.z;
    const int e = e0 + ez;
    const int m0 = blockIdx.y * BM;
    const int nkept = cnt[e * 2 + kk];
    if (m0 >= nkept) return;
    const int n0 = blockIdx.x * BN;
    const int sbase = e * CAP2 + kk * CAP + m0;
    const size_t hbase = (size_t)ez * CAP2 + kk * CAP + m0;

    __shared__ __align__(1024) unsigned short smem[16384];   // 32 KB: A|B
    __shared__ int tokL[BM];
    __shared__ float wL[BM];

    const int tid = threadIdx.x, wid = tid >> 6, lane = tid & 63;
    if (tid < BM) {
        tokL[tid] = tok_list[sbase + tid];
        wL[tid] = w_list[sbase + tid];
    }

    const unsigned short* gsrc[8];
    int ldsoff[8];
#pragma unroll
    for (int i = 0; i < 8; ++i) {
        const int f = (wid * 8 + i) * 64 + lane;   // 16B slot index, 0..2047
        const unsigned short* g;
        if (f < 1024) {          // A region: h rows, 128 rows x 8 chunks
            const int r = f >> 3, c = (f & 7) ^ (r & 7);
            g = h_ws + (hbase + r) * H_DIM + c * 8;
        } else {                 // B region: wd rows
            const int fr = f - 1024;
            const int r = fr >> 3, c = (fr & 7) ^ (r & 7);
            g = wdbf + ((size_t)e * D_DIM + n0 + r) * H_DIM + c * 8;
        }
        gsrc[i] = g;
        ldsoff[i] = (wid * 8 + i) * 1024;   // bytes, wave-uniform
    }

    float4v acc[4][4];
#pragma unroll
    for (int i = 0; i < 4; ++i)
#pragma unroll
        for (int j = 0; j < 4; ++j) acc[i][j] = (float4v){0.f, 0.f, 0.f, 0.f};

    const int wm = (wid & 1) * 64, wn = (wid >> 1) * 64;
    const int frow = lane & 15;
    const int quad = lane >> 4;

    for (int k0 = 0; k0 < H_DIM; k0 += 64) {
#pragma unroll
        for (int i = 0; i < 8; ++i)
            __builtin_amdgcn_global_load_lds(
                (gu32*)(gsrc[i] + k0),
                (lu32*)((char*)smem + ldsoff[i]), 16, 0, 0);
        __syncthreads();

        short8 af[2][4], bf[2][4];
#pragma unroll
        for (int s = 0; s < 2; ++s) {
            const int c = s * 4 + quad;
#pragma unroll
            for (int i = 0; i < 4; ++i) {
                const int row = wm + i * 16 + frow;
                af[s][i] = *(const short8*)&smem[(row * 8 + (c ^ (row & 7))) * 8];
            }
#pragma unroll
            for (int j = 0; j < 4; ++j) {
                const int row = wn + j * 16 + frow;
                bf[s][j] = *(const short8*)&smem[8192 + (row * 8 + (c ^ (row & 7))) * 8];
            }
        }
#pragma unroll
        for (int s = 0; s < 2; ++s)
#pragma unroll
            for (int i = 0; i < 4; ++i)
#pragma unroll
                for (int j = 0; j < 4; ++j)
                    acc[i][j] = __builtin_amdgcn_mfma_f32_16x16x32_bf16(af[s][i], bf[s][j], acc[i][j], 0, 0, 0);
        __syncthreads();
    }

    // Epilogue: plain store (kk=0) or load-add-store (kk=1); pad rows masked.
    const int col = lane & 15, rbase = (lane >> 4) * 4;
#pragma unroll
    for (int i = 0; i < 4; ++i)
#pragma unroll
        for (int r = 0; r < 4; ++r) {
            const int m = wm + i * 16 + rbase + r;
            if (m0 + m >= nkept) continue;       // pad row: skip (avoid races)
            const float wRow = wL[m];
            float* orow = out + (size_t)tokL[m] * D_DIM + n0;
#pragma unroll
            for (int j = 0; j < 4; ++j) {
                const int n = j * 16 + wn + col;
                const float v = acc[i][j][r] * wRow;
                if (kk == 0) orow[n] = v;
                else         orow[n] += v;
            }
        }
}

// ---------------------------------------------------------------------------
// Legacy fp32-staging kernels (fallback if workspace too small for bf16 path)
// ---------------------------------------------------------------------------
__global__ __launch_bounds__(256, 2) void gateup_legacy_k(
    const float* __restrict__ x,
    const float* __restrict__ wg_all, const float* __restrict__ wu_all,
    const int* __restrict__ tok_list, const int* __restrict__ cnt,
    unsigned short* __restrict__ h_ws, int e0) {
    const int ez = blockIdx.z;
    const int e = e0 + ez;
    const int kk = blockIdx.y / MT_K;
    const int m0 = (blockIdx.y - kk * MT_K) * BM;
    if (m0 >= cnt[e * 2 + kk]) return;
    const int n0 = blockIdx.x * BN;
    const int sbase = e * CAP2 + kk * CAP + m0;
    const size_t hbase = (size_t)ez * CAP2 + kk * CAP + m0;

    __shared__ __align__(16) unsigned short As[BM][BK];
    __shared__ __align__(16) unsigned short Bg[BN][BK];
    __shared__ __align__(16) unsigned short Bu[BN][BK];
    __shared__ int tokL[BM];

    const int tid = threadIdx.x;
    if (tid < BM) tokL[tid] = tok_list[sbase + tid];
    __syncthreads();

    const float* wg = wg_all + (size_t)e * H_DIM * D_DIM;
    const float* wu = wu_all + (size_t)e * H_DIM * D_DIM;

    const float* aSrc[4]; const float* gSrc[4]; const float* uSrc[4];
    unsigned short* aDst[4]; unsigned short* gDst[4]; unsigned short* uDst[4];
#pragma unroll
    for (int it = 0; it < 4; ++it) {
        const int fid = it * 256 + tid;
        const int row = fid >> 3;
        const int c4 = (fid & 7) * 4;
        aSrc[it] = x + (size_t)tokL[row] * D_DIM + c4;
        gSrc[it] = wg + (size_t)(n0 + row) * D_DIM + c4;
        uSrc[it] = wu + (size_t)(n0 + row) * D_DIM + c4;
        aDst[it] = &As[row][c4];
        gDst[it] = &Bg[row][c4];
        uDst[it] = &Bu[row][c4];
    }

    float4v accg[4][4], accu[4][4];
#pragma unroll
    for (int i = 0; i < 4; ++i)
#pragma unroll
        for (int j = 0; j < 4; ++j) {
            accg[i][j] = (float4v){0.f, 0.f, 0.f, 0.f};
            accu[i][j] = (float4v){0.f, 0.f, 0.f, 0.f};
        }

    const int wid = tid >> 6, lane = tid & 63;
    const int wm = (wid & 1) * 64, wn = (wid >> 1) * 64;
    const int frow = lane & 15;
    const int fk = (lane >> 4) * 8;

    for (int k0 = 0; k0 < D_DIM; k0 += BK) {
#pragma unroll
        for (int it = 0; it < 4; ++it) {
            store4bf(aDst[it], *(const float4*)(aSrc[it] + k0));
            store4bf(gDst[it], *(const float4*)(gSrc[it] + k0));
            store4bf(uDst[it], *(const float4*)(uSrc[it] + k0));
        }
        __syncthreads();
        short8 af[4], bgf[4], buf[4];
#pragma unroll
        for (int i = 0; i < 4; ++i)
            af[i] = *(const short8*)&As[wm + i * 16 + frow][fk];
#pragma unroll
        for (int j = 0; j < 4; ++j) {
            bgf[j] = *(const short8*)&Bg[wn + j * 16 + frow][fk];
            buf[j] = *(const short8*)&Bu[wn + j * 16 + frow][fk];
        }
#pragma unroll
        for (int i = 0; i < 4; ++i)
#pragma unroll
            for (int j = 0; j < 4; ++j) {
                accg[i][j] = __builtin_amdgcn_mfma_f32_16x16x32_bf16(af[i], bgf[j], accg[i][j], 0, 0, 0);
                accu[i][j] = __builtin_amdgcn_mfma_f32_16x16x32_bf16(af[i], buf[j], accu[i][j], 0, 0, 0);
            }
        __syncthreads();
    }

    const int col = lane & 15, rbase = (lane >> 4) * 4;
#pragma unroll
    for (int i = 0; i < 4; ++i)
#pragma unroll
        for (int j = 0; j < 4; ++j)
#pragma unroll
            for (int r = 0; r < 4; ++r) {
                const float g = accg[i][j][r];
                const float u = accu[i][j][r];
                const float hv = (g / (1.f + __expf(-g))) * u;
                const int m = wm + i * 16 + rbase + r;
                const int n = wn + j * 16 + col;
                h_ws[(hbase + m) * H_DIM + (n0 + n)] = f2bf(hv);
            }
}

__global__ __launch_bounds__(256, 2) void down_legacy_k(
    const unsigned short* __restrict__ h_ws, const float* __restrict__ wd_all,
    const int* __restrict__ tok_list, const float* __restrict__ w_list,
    const int* __restrict__ cnt, float* __restrict__ out, int e0) {
    const int ez = blockIdx.z;
    const int e = e0 + ez;
    const int kk = blockIdx.y / MT_K;
    const int m0 = (blockIdx.y - kk * MT_K) * BM;
    if (m0 >= cnt[e * 2 + kk]) return;
    const int n0 = blockIdx.x * BN;
    const int sbase = e * CAP2 + kk * CAP + m0;
    const size_t hbase = (size_t)ez * CAP2 + kk * CAP + m0;

    __shared__ __align__(16) unsigned short As[BM][BK];
    __shared__ __align__(16) unsigned short Bs[BN][BK];
    __shared__ int tokL[BM];
    __shared__ float wL[BM];

    const int tid = threadIdx.x;
    if (tid < BM) {
        tokL[tid] = tok_list[sbase + tid];
        wL[tid] = w_list[sbase + tid];
    }
    __syncthreads();

    const unsigned short* hA = h_ws + hbase * H_DIM;
    const float* wd = wd_all + (size_t)e * D_DIM * H_DIM;

    const unsigned short* aSrc[2]; unsigned short* aDst[2];
#pragma unroll
    for (int it = 0; it < 2; ++it) {
        const int fid = it * 256 + tid;
        const int row = fid >> 2;
        const int c8 = (fid & 3) * 8;
        aSrc[it] = hA + (size_t)row * H_DIM + c8;
        aDst[it] = &As[row][c8];
    }
    const float* bSrc[4]; unsigned short* bDst[4];
#pragma unroll
    for (int it = 0; it < 4; ++it) {
        const int fid = it * 256 + tid;
        const int row = fid >> 3;
        const int c4 = (fid & 7) * 4;
        bSrc[it] = wd + (size_t)(n0 + row) * H_DIM + c4;
        bDst[it] = &Bs[row][c4];
    }

    float4v acc[4][4];
#pragma unroll
    for (int i = 0; i < 4; ++i)
#pragma unroll
        for (int j = 0; j < 4; ++j) acc[i][j] = (float4v){0.f, 0.f, 0.f, 0.f};

    const int wid = tid >> 6, lane = tid & 63;
    const int wm = (wid & 1) * 64, wn = (wid >> 1) * 64;
    const int frow = lane & 15;
    const int fk = (lane >> 4) * 8;

    for (int k0 = 0; k0 < H_DIM; k0 += BK) {
#pragma unroll
        for (int it = 0; it < 2; ++it)
            *(uint4*)aDst[it] = *(const uint4*)(aSrc[it] + k0);
#pragma unroll
        for (int it = 0; it < 4; ++it)
            store4bf(bDst[it], *(const float4*)(bSrc[it] + k0));
        __syncthreads();
        short8 af[4], bf[4];
#pragma unroll
        for (int i = 0; i < 4; ++i)
            af[i] = *(const short8*)&As[wm + i * 16 + frow][fk];
#pragma unroll
        for (int j = 0; j < 4; ++j)
            bf[j] = *(const short8*)&Bs[wn + j * 16 + frow][fk];
#pragma unroll
        for (int i = 0; i < 4; ++i)
#pragma unroll
            for (int j = 0; j < 4; ++j)
                acc[i][j] = __builtin_amdgcn_mfma_f32_16x16x32_bf16(af[i], bf[j], acc[i][j], 0, 0, 0);
        __syncthreads();
    }

    const int col = lane & 15, rbase = (lane >> 4) * 4;
#pragma unroll
    for (int i = 0; i < 4; ++i)
#pragma unroll
        for (int j = 0; j < 4; ++j)
#pragma unroll
            for (int r = 0; r < 4; ++r) {
                const int m = wm + i * 16 + rbase + r;
                const int n = wn + j * 16 + col;
                const float v = acc[i][j][r] * wL[m];
                unsafeAtomicAdd(&out[(size_t)tokL[m] * D_DIM + n0 + n], v);
            }
}

// ---------------------------------------------------------------------------
extern "C" void kernel_launch(void* const* d_in, const int* in_sizes, int n_in,
                              void* d_out, int out_size, void* d_ws, size_t ws_size,
                              hipStream_t stream) {
    const float* x        = (const float*)d_in[0];
    const float* gate_w   = (const float*)d_in[1];
    const float* gate_pw  = (const float*)d_in[2];
    const float* up_pw    = (const float*)d_in[3];
    const float* down_pw  = (const float*)d_in[4];
    float* out = (float*)d_out;
    (void)n_in; (void)in_sizes; (void)out_size;

    uint8_t* ws = (uint8_t*)d_ws;
    size_t off = 0;
    int*   topi     = (int*)(ws + off);   off += (size_t)T_TOK * 2 * 4;
    float* topw     = (float*)(ws + off); off += (size_t)T_TOK * 2 * 4;
    int*   tok_list = (int*)(ws + off);   off += (size_t)E_NUM * CAP2 * 4;
    float* w_list   = (float*)(ws + off); off += (size_t)E_NUM * CAP2 * 4;
    int*   cnt      = (int*)(ws + off);   off += 256;
    off = (off + 4095) & ~(size_t)4095;
    const size_t routing_end = off;

    const size_t x_elems = (size_t)T_TOK * D_DIM;           // 8.4 M
    const size_t w_elems = (size_t)E_NUM * H_DIM * D_DIM;   // 16.8 M each
    unsigned short* xbf  = (unsigned short*)(ws + off); off += x_elems * 2;
    unsigned short* wgbf = (unsigned short*)(ws + off); off += w_elems * 2;
    unsigned short* wubf = (unsigned short*)(ws + off); off += w_elems * 2;
    unsigned short* wdbf = (unsigned short*)(ws + off); off += w_elems * 2;
    const size_t need_base = off;                           // ~118 MB
    const size_t per_e = (size_t)CAP2 * H_DIM * 2;          // 10.5 MB / expert

    hipMemsetAsync(out, 0, (size_t)T_TOK * D_DIM * sizeof(float), stream);

    if (ws_size >= need_base + per_e) {
        // bf16 fast path
        unsigned short* h_ws = (unsigned short*)(ws + need_base);
        int chunk = (int)((ws_size - need_base) / per_e);
        if (chunk > E_NUM) chunk = E_NUM;

        router_k<<<T_TOK / 4, 256, 0, stream>>>(x, gate_w, topi, topw, xbf);
        assign_k<<<1, 1024, 0, stream>>>(topi, topw, tok_list, w_list, cnt);
        convert_w_k<<<4096, 256, 0, stream>>>(gate_pw, up_pw, down_pw,
                                              wgbf, wubf, wdbf);

        for (int e0 = 0; e0 < E_NUM; e0 += chunk) {
            const int ne = (e0 + chunk <= E_NUM) ? chunk : (E_NUM - e0);
            dim3 g1(H_DIM / BN, 2 * MT_K, ne);
            gateup_bf_k<<<g1, 256, 0, stream>>>(xbf, wgbf, wubf, tok_list, cnt, h_ws, e0);
            dim3 g2(D_DIM / BN, MT_K, ne);
            down_bf_k<<<g2, 256, 0, stream>>>(h_ws, wdbf, tok_list, w_list, cnt, out, e0, 0);
            down_bf_k<<<g2, 256, 0, stream>>>(h_ws, wdbf, tok_list, w_list, cnt, out, e0, 1);
        }
    } else {
        // legacy fp32-staging path (small workspace)
        unsigned short* h_ws = (unsigned short*)(ws + routing_end);
        int chunk = (ws_size > routing_end) ? (int)((ws_size - routing_end) / per_e) : 0;
        if (chunk > E_NUM) chunk = E_NUM;
        if (chunk < 1) chunk = 1;

        router_k<<<T_TOK / 4, 256, 0, stream>>>(x, gate_w, topi, topw, xbf);
        assign_k<<<1, 1024, 0, stream>>>(topi, topw, tok_list, w_list, cnt);

        for (int e0 = 0; e0 < E_NUM; e0 += chunk) {
            const int ne = (e0 + chunk <= E_NUM) ? chunk : (E_NUM - e0);
            dim3 g1(H_DIM / BN, 2 * MT_K, ne);
            gateup_legacy_k<<<g1, 256, 0, stream>>>(x, gate_pw, up_pw, tok_list, cnt, h_ws, e0);
            dim3 g2(D_DIM / BN, 2 * MT_K, ne);
            down_legacy_k<<<g2, 256, 0, stream>>>(h_ws, down_pw, tok_list, w_list, cnt, out, e0);
        }
    }
}